// Round 1
// baseline (22901.236 us; speedup 1.0000x reference)
//
#include <hip/hip_runtime.h>

#define HD 384
#define HHD 192

__device__ __forceinline__ float gelu_f(float x) {
    return 0.5f * x * (1.0f + erff(x * 0.70710678118654752f));
}

__device__ __forceinline__ float sigmoid_f(float x) {
    return 1.0f / (1.0f + expf(-x));
}

// ---------------- SpMM: out[rows[e]] += vals[e] * in[cols[e], :] ----------------
// One thread per (edge, 4-col chunk): 96 chunks of float4 per edge.
__global__ __launch_bounds__(256) void spmm_atomic(
        const int* __restrict__ rows, const int* __restrict__ cols,
        const float* __restrict__ vals, const float* __restrict__ in,
        float* __restrict__ out, int nnz) {
    long long t = (long long)blockIdx.x * blockDim.x + threadIdx.x;
    int e = (int)(t / 96);
    if (e >= nnz) return;
    int c = (int)(t % 96) * 4;
    int r = rows[e], cl = cols[e];
    float v = vals[e];
    float4 x = *reinterpret_cast<const float4*>(in + (long long)cl * HD + c);
    float* o = out + (long long)r * HD + c;
    atomicAdd(o + 0, v * x.x);
    atomicAdd(o + 1, v * x.y);
    atomicAdd(o + 2, v * x.z);
    atomicAdd(o + 3, v * x.w);
}

// ---------------- out = gelu(LN(in @ W, g, b)); 8 rows per block ----------------
__global__ __launch_bounds__(384) void gemm_ln_gelu(
        const float* __restrict__ in, const float* __restrict__ W,
        const float* __restrict__ g, const float* __restrict__ b,
        float* __restrict__ out, int nrows) {
    __shared__ float xs[8][HD];
    __shared__ float rs[6][8], rq[6][8];
    __shared__ float mean_s[8], rstd_s[8];
    const int j = threadIdx.x;          // 0..383 output column
    const int row0 = blockIdx.x * 8;
    const int wave = j >> 6, lane = j & 63;

    #pragma unroll
    for (int r = 0; r < 8; ++r) {
        int row = row0 + r;
        xs[r][j] = (row < nrows) ? in[(long long)row * HD + j] : 0.0f;
    }
    __syncthreads();

    float acc[8];
    #pragma unroll
    for (int r = 0; r < 8; ++r) acc[r] = 0.0f;

    for (int k = 0; k < HD; k += 4) {
        float w0 = W[(k + 0) * HD + j];
        float w1 = W[(k + 1) * HD + j];
        float w2 = W[(k + 2) * HD + j];
        float w3 = W[(k + 3) * HD + j];
        #pragma unroll
        for (int r = 0; r < 8; ++r) {
            float4 x4 = *reinterpret_cast<const float4*>(&xs[r][k]);
            acc[r] = fmaf(x4.x, w0, acc[r]);
            acc[r] = fmaf(x4.y, w1, acc[r]);
            acc[r] = fmaf(x4.z, w2, acc[r]);
            acc[r] = fmaf(x4.w, w3, acc[r]);
        }
    }

    // LayerNorm reductions: per row r, mean/var over the 384 columns.
    #pragma unroll
    for (int r = 0; r < 8; ++r) {
        float s = acc[r], q = acc[r] * acc[r];
        #pragma unroll
        for (int o = 32; o > 0; o >>= 1) {
            s += __shfl_xor(s, o);
            q += __shfl_xor(q, o);
        }
        if (lane == 0) { rs[wave][r] = s; rq[wave][r] = q; }
    }
    __syncthreads();
    if (j < 8) {
        float s = 0.0f, q = 0.0f;
        #pragma unroll
        for (int w = 0; w < 6; ++w) { s += rs[w][j]; q += rq[w][j]; }
        float m = s * (1.0f / HD);
        float v = q * (1.0f / HD) - m * m;
        mean_s[j] = m;
        rstd_s[j] = rsqrtf(v + 1e-5f);
    }
    __syncthreads();

    float gj = g[j], bj = b[j];
    #pragma unroll
    for (int r = 0; r < 8; ++r) {
        int row = row0 + r;
        if (row < nrows) {
            float y = (acc[r] - mean_s[r]) * rstd_s[r] * gj + bj;
            out[(long long)row * HD + j] = gelu_f(y);
        }
    }
}

// ---------------- word_H = 0.35*emb + 0.65*h ----------------
__global__ __launch_bounds__(256) void axpby_kernel(
        const float* __restrict__ a, const float* __restrict__ h,
        float* __restrict__ o, int n4) {
    int i = blockIdx.x * blockDim.x + threadIdx.x;
    if (i >= n4) return;
    float4 x = reinterpret_cast<const float4*>(a)[i];
    float4 y = reinterpret_cast<const float4*>(h)[i];
    float4 r;
    r.x = 0.35f * x.x + 0.65f * y.x;
    r.y = 0.35f * x.y + 0.65f * y.y;
    r.z = 0.35f * x.z + 0.65f * y.z;
    r.w = 0.35f * x.w + 0.65f * y.w;
    reinterpret_cast<float4*>(o)[i] = r;
}

// ---------------- fused doc head: gate -> mix -> MLP -> LN -> classifier ----------------
__global__ __launch_bounds__(384) void doc_head(
        const float* __restrict__ docH, const float* __restrict__ docH0,
        const float* __restrict__ gW1, const float* __restrict__ gb1,
        const float* __restrict__ gW2, const float* __restrict__ gb2,
        const float* __restrict__ mW1, const float* __restrict__ mb1,
        const float* __restrict__ mg, const float* __restrict__ mbn,
        const float* __restrict__ mW2, const float* __restrict__ mb2,
        const float* __restrict__ cW, const float* __restrict__ cb,
        float* __restrict__ out, int ndocs) {
    const int d = blockIdx.x;
    const int j = threadIdx.x;          // 0..383
    if (d >= ndocs) return;
    __shared__ float xin[2 * HD];
    __shared__ float t1[HD];
    __shared__ float ds[HD];
    __shared__ float vs[HHD];
    __shared__ float rs[6], rq[6];
    __shared__ float mean_s, rstd_s;
    const int wave = j >> 6, lane = j & 63;

    xin[j]      = docH [(long long)d * HD + j];
    xin[HD + j] = docH0[(long long)d * HD + j];
    __syncthreads();

    // t1 = gelu(gate_in @ gate_W1 + gate_b1), gate_W1 is [768][384]
    float acc = gb1[j];
    for (int k = 0; k < 2 * HD; ++k) acc = fmaf(xin[k], gW1[k * HD + j], acc);
    t1[j] = gelu_f(acc);
    __syncthreads();

    // gate = sigmoid(t1 @ gate_W2 + gate_b2); doc = gate*docH + (1-gate)*docH0
    acc = gb2[j];
    for (int k = 0; k < HD; ++k) acc = fmaf(t1[k], gW2[k * HD + j], acc);
    float gate = sigmoid_f(acc);
    float docv = gate * xin[j] + (1.0f - gate) * xin[HD + j];
    ds[j] = docv;
    __syncthreads();

    // u = gelu(doc @ mlp_W1 + mlp_b1)
    acc = mb1[j];
    for (int k = 0; k < HD; ++k) acc = fmaf(ds[k], mW1[k * HD + j], acc);
    float u = gelu_f(acc);

    // LayerNorm(u)
    float s = u, q = u * u;
    #pragma unroll
    for (int o = 32; o > 0; o >>= 1) {
        s += __shfl_xor(s, o);
        q += __shfl_xor(q, o);
    }
    if (lane == 0) { rs[wave] = s; rq[wave] = q; }
    __syncthreads();
    if (j == 0) {
        float ss = 0.0f, qq = 0.0f;
        #pragma unroll
        for (int w = 0; w < 6; ++w) { ss += rs[w]; qq += rq[w]; }
        float m = ss * (1.0f / HD);
        mean_s = m;
        rstd_s = rsqrtf(qq * (1.0f / HD) - m * m + 1e-5f);
    }
    __syncthreads();
    float un = (u - mean_s) * rstd_s * mg[j] + mbn[j];
    t1[j] = un;                 // reuse t1 for normalized vector
    __syncthreads();

    // v = gelu(un @ mlp_W2 + mlp_b2), mlp_W2 is [384][192]
    if (j < HHD) {
        acc = mb2[j];
        for (int k = 0; k < HD; ++k) acc = fmaf(t1[k], mW2[k * HHD + j], acc);
        vs[j] = gelu_f(acc);
    }
    __syncthreads();

    // logits = v @ cls_W + cls_b, cls_W is [192][2]
    if (j < 2) {
        acc = cb[j];
        for (int k = 0; k < HHD; ++k) acc = fmaf(vs[k], cW[k * 2 + j], acc);
        out[(long long)d * 2 + j] = acc;
    }
}

extern "C" void kernel_launch(void* const* d_in, const int* in_sizes, int n_in,
                              void* d_out, int out_size, void* d_ws, size_t ws_size,
                              hipStream_t stream) {
    const int*   A_rows = (const int*)  d_in[0];
    const int*   A_cols = (const int*)  d_in[1];
    const float* A_vals = (const float*)d_in[2];
    const int*   X_rows = (const int*)  d_in[3];
    const int*   X_cols = (const int*)  d_in[4];
    const float* X_vals = (const float*)d_in[5];
    // d_in[6] = num_docs scalar (derived from out_size instead)
    const float* emb    = (const float*)d_in[7];
    const float* W1     = (const float*)d_in[8];
    const float* W2     = (const float*)d_in[9];
    const float* W3     = (const float*)d_in[10];
    const float* g1     = (const float*)d_in[11];
    const float* b1     = (const float*)d_in[12];
    const float* g2     = (const float*)d_in[13];
    const float* b2     = (const float*)d_in[14];
    const float* g3     = (const float*)d_in[15];
    const float* b3     = (const float*)d_in[16];
    const float* mW1    = (const float*)d_in[17];
    const float* mb1    = (const float*)d_in[18];
    const float* mg     = (const float*)d_in[19];
    const float* mbn    = (const float*)d_in[20];
    const float* mW2    = (const float*)d_in[21];
    const float* mb2    = (const float*)d_in[22];
    const float* cW     = (const float*)d_in[23];
    const float* cb     = (const float*)d_in[24];
    const float* gW1    = (const float*)d_in[25];
    const float* gb1    = (const float*)d_in[26];
    const float* gW2    = (const float*)d_in[27];
    const float* gb2    = (const float*)d_in[28];

    const int E_   = in_sizes[0];
    const int NNZ_ = in_sizes[3];
    const int N_   = in_sizes[7] / HD;
    const int D_   = out_size / 2;

    float* buf1 = (float*)d_ws;                       // [N, H]
    float* buf2 = buf1 + (size_t)N_ * HD;             // [N, H]
    float* dbuf1 = buf2;                              // [D, H] (aliases buf2 after word_H)
    float* dbuf2 = buf2 + (size_t)D_ * HD;            // [D, H]
    float* logits = (float*)d_out;

    const size_t nh_bytes = (size_t)N_ * HD * sizeof(float);
    const int spmmA_grid = (int)(((long long)E_ * 96 + 255) / 256);
    const int spmmX_grid = (int)(((long long)NNZ_ * 96 + 255) / 256);
    const int gemm_grid = (N_ + 7) / 8;
    const int n4 = N_ * HD / 4;

    // --- GCN block 1 ---
    hipMemsetAsync(buf1, 0, nh_bytes, stream);
    spmm_atomic<<<spmmA_grid, 256, 0, stream>>>(A_rows, A_cols, A_vals, emb, buf1, E_);
    gemm_ln_gelu<<<gemm_grid, 384, 0, stream>>>(buf1, W1, g1, b1, buf2, N_);
    // --- GCN block 2 ---
    hipMemsetAsync(buf1, 0, nh_bytes, stream);
    spmm_atomic<<<spmmA_grid, 256, 0, stream>>>(A_rows, A_cols, A_vals, buf2, buf1, E_);
    gemm_ln_gelu<<<gemm_grid, 384, 0, stream>>>(buf1, W2, g2, b2, buf2, N_);
    // --- GCN block 3 ---
    hipMemsetAsync(buf1, 0, nh_bytes, stream);
    spmm_atomic<<<spmmA_grid, 256, 0, stream>>>(A_rows, A_cols, A_vals, buf2, buf1, E_);
    gemm_ln_gelu<<<gemm_grid, 384, 0, stream>>>(buf1, W3, g3, b3, buf2, N_);

    // --- word_H = 0.35*emb + 0.65*h  (into buf1; buf2 then becomes free) ---
    axpby_kernel<<<(n4 + 255) / 256, 256, 0, stream>>>(emb, buf2, buf1, n4);

    // --- doc aggregation (dbuf1/dbuf2 alias buf2; D*H*2 == N*H) ---
    hipMemsetAsync(buf2, 0, nh_bytes, stream);
    spmm_atomic<<<spmmX_grid, 256, 0, stream>>>(X_rows, X_cols, X_vals, buf1, dbuf1, NNZ_);
    spmm_atomic<<<spmmX_grid, 256, 0, stream>>>(X_rows, X_cols, X_vals, emb, dbuf2, NNZ_);

    // --- fused doc head ---
    doc_head<<<D_, 384, 0, stream>>>(dbuf1, dbuf2,
                                     gW1, gb1, gW2, gb2,
                                     mW1, mb1, mg, mbn, mW2, mb2,
                                     cW, cb, logits, D_);
}

// Round 2
// 4178.061 us; speedup vs baseline: 5.4813x; 5.4813x over previous
//
#include <hip/hip_runtime.h>

#define HD 384
#define HHD 192

__device__ __forceinline__ float gelu_f(float x) {
    return 0.5f * x * (1.0f + erff(x * 0.70710678118654752f));
}

__device__ __forceinline__ float sigmoid_f(float x) {
    return 1.0f / (1.0f + expf(-x));
}

// ---------------- CSR build: histogram + scan + scatter ----------------
__global__ __launch_bounds__(256) void hist_rows(
        const int* __restrict__ rows, int* __restrict__ cnt, int nnz) {
    int e = blockIdx.x * blockDim.x + threadIdx.x;
    if (e < nnz) atomicAdd(&cnt[rows[e]], 1);
}

// per-block (256-wide) exclusive scan; block sums out
__global__ __launch_bounds__(256) void scan_local(
        const int* __restrict__ cnt, int* __restrict__ rp,
        int* __restrict__ bsum, int n) {
    __shared__ int wsum[4];
    int i = blockIdx.x * 256 + threadIdx.x;
    int lane = threadIdx.x & 63, wv = threadIdx.x >> 6;
    int v = (i < n) ? cnt[i] : 0;
    int s = v;
    #pragma unroll
    for (int o = 1; o < 64; o <<= 1) {
        int t = __shfl_up(s, o);
        if (lane >= o) s += t;
    }
    if (lane == 63) wsum[wv] = s;
    __syncthreads();
    int woff = 0;
    for (int w = 0; w < wv; ++w) woff += wsum[w];
    if (i < n) rp[i] = woff + s - v;
    if (threadIdx.x == 255) bsum[blockIdx.x] = woff + s;
}

// single-block scan of block sums (nb <= 256); writes grand total to *total_out
__global__ __launch_bounds__(256) void scan_bsums(
        const int* __restrict__ bsum, int* __restrict__ boff,
        int nb, int* __restrict__ total_out) {
    __shared__ int tmp[256];
    int tid = threadIdx.x;
    int v = (tid < nb) ? bsum[tid] : 0;
    tmp[tid] = v;
    __syncthreads();
    for (int o = 1; o < 256; o <<= 1) {
        int t = (tid >= o) ? tmp[tid - o] : 0;
        __syncthreads();
        tmp[tid] += t;
        __syncthreads();
    }
    if (tid < nb) boff[tid] = tmp[tid] - v;
    if (tid == nb - 1) *total_out = tmp[tid];
}

__global__ __launch_bounds__(256) void scan_add(
        int* __restrict__ rp, const int* __restrict__ boff, int n) {
    int i = blockIdx.x * 256 + threadIdx.x;
    if (i < n) rp[i] += boff[i >> 8];
}

__global__ __launch_bounds__(256) void csr_scatter(
        const int* __restrict__ rows, const int* __restrict__ cols,
        const float* __restrict__ vals, const int* __restrict__ rp,
        int* __restrict__ fill, int* __restrict__ cp,
        float* __restrict__ vp, int nnz) {
    int e = blockIdx.x * blockDim.x + threadIdx.x;
    if (e >= nnz) return;
    int r = rows[e];
    int pos = rp[r] + atomicAdd(&fill[r], 1);
    cp[pos] = cols[e];
    vp[pos] = vals[e];
}

// ---------------- SpMM (CSR gather): out[r,:] = sum_p vals[p] * in[cols[p],:] ----------------
__global__ __launch_bounds__(384) void spmm_csr(
        const int* __restrict__ rp, const int* __restrict__ cp,
        const float* __restrict__ vp, const float* __restrict__ in,
        float* __restrict__ out, int nrows) {
    const int r = blockIdx.x;
    const int j = threadIdx.x;
    const int s = rp[r], e = rp[r + 1];
    float acc = 0.0f;
    for (int p = s; p < e; ++p) {
        int c = cp[p];
        float v = vp[p];
        acc = fmaf(v, in[(size_t)c * HD + j], acc);
    }
    out[(size_t)r * HD + j] = acc;
}

// ---------------- out = gelu(LN(in @ W, g, b)); 8 rows per block ----------------
__global__ __launch_bounds__(384) void gemm_ln_gelu(
        const float* __restrict__ in, const float* __restrict__ W,
        const float* __restrict__ g, const float* __restrict__ b,
        float* __restrict__ out, int nrows) {
    __shared__ float xs[8][HD];
    __shared__ float rs[6][8], rq[6][8];
    __shared__ float mean_s[8], rstd_s[8];
    const int j = threadIdx.x;          // 0..383 output column
    const int row0 = blockIdx.x * 8;
    const int wave = j >> 6, lane = j & 63;

    #pragma unroll
    for (int r = 0; r < 8; ++r) {
        int row = row0 + r;
        xs[r][j] = (row < nrows) ? in[(long long)row * HD + j] : 0.0f;
    }
    __syncthreads();

    float acc[8];
    #pragma unroll
    for (int r = 0; r < 8; ++r) acc[r] = 0.0f;

    for (int k = 0; k < HD; k += 4) {
        float w0 = W[(k + 0) * HD + j];
        float w1 = W[(k + 1) * HD + j];
        float w2 = W[(k + 2) * HD + j];
        float w3 = W[(k + 3) * HD + j];
        #pragma unroll
        for (int r = 0; r < 8; ++r) {
            float4 x4 = *reinterpret_cast<const float4*>(&xs[r][k]);
            acc[r] = fmaf(x4.x, w0, acc[r]);
            acc[r] = fmaf(x4.y, w1, acc[r]);
            acc[r] = fmaf(x4.z, w2, acc[r]);
            acc[r] = fmaf(x4.w, w3, acc[r]);
        }
    }

    #pragma unroll
    for (int r = 0; r < 8; ++r) {
        float s = acc[r], q = acc[r] * acc[r];
        #pragma unroll
        for (int o = 32; o > 0; o >>= 1) {
            s += __shfl_xor(s, o);
            q += __shfl_xor(q, o);
        }
        if (lane == 0) { rs[wave][r] = s; rq[wave][r] = q; }
    }
    __syncthreads();
    if (j < 8) {
        float s = 0.0f, q = 0.0f;
        #pragma unroll
        for (int w = 0; w < 6; ++w) { s += rs[w][j]; q += rq[w][j]; }
        float m = s * (1.0f / HD);
        float v = q * (1.0f / HD) - m * m;
        mean_s[j] = m;
        rstd_s[j] = rsqrtf(v + 1e-5f);
    }
    __syncthreads();

    float gj = g[j], bj = b[j];
    #pragma unroll
    for (int r = 0; r < 8; ++r) {
        int row = row0 + r;
        if (row < nrows) {
            float y = (acc[r] - mean_s[r]) * rstd_s[r] * gj + bj;
            out[(long long)row * HD + j] = gelu_f(y);
        }
    }
}

// ---------------- word_H = 0.35*emb + 0.65*h ----------------
__global__ __launch_bounds__(256) void axpby_kernel(
        const float* __restrict__ a, const float* __restrict__ h,
        float* __restrict__ o, int n4) {
    int i = blockIdx.x * blockDim.x + threadIdx.x;
    if (i >= n4) return;
    float4 x = reinterpret_cast<const float4*>(a)[i];
    float4 y = reinterpret_cast<const float4*>(h)[i];
    float4 r;
    r.x = 0.35f * x.x + 0.65f * y.x;
    r.y = 0.35f * x.y + 0.65f * y.y;
    r.z = 0.35f * x.z + 0.65f * y.z;
    r.w = 0.35f * x.w + 0.65f * y.w;
    reinterpret_cast<float4*>(o)[i] = r;
}

// ---------------- fused doc head: gate -> mix -> MLP -> LN -> classifier ----------------
__global__ __launch_bounds__(384) void doc_head(
        const float* __restrict__ docH, const float* __restrict__ docH0,
        const float* __restrict__ gW1, const float* __restrict__ gb1,
        const float* __restrict__ gW2, const float* __restrict__ gb2,
        const float* __restrict__ mW1, const float* __restrict__ mb1,
        const float* __restrict__ mg, const float* __restrict__ mbn,
        const float* __restrict__ mW2, const float* __restrict__ mb2,
        const float* __restrict__ cW, const float* __restrict__ cb,
        float* __restrict__ out, int ndocs) {
    const int d = blockIdx.x;
    const int j = threadIdx.x;          // 0..383
    __shared__ float xin[2 * HD];
    __shared__ float t1[HD];
    __shared__ float ds[HD];
    __shared__ float vs[HHD];
    __shared__ float rs[6], rq[6];
    __shared__ float mean_s, rstd_s;
    const int wave = j >> 6, lane = j & 63;

    xin[j]      = docH [(long long)d * HD + j];
    xin[HD + j] = docH0[(long long)d * HD + j];
    __syncthreads();

    float acc = gb1[j];
    for (int k = 0; k < 2 * HD; ++k) acc = fmaf(xin[k], gW1[k * HD + j], acc);
    t1[j] = gelu_f(acc);
    __syncthreads();

    acc = gb2[j];
    for (int k = 0; k < HD; ++k) acc = fmaf(t1[k], gW2[k * HD + j], acc);
    float gate = sigmoid_f(acc);
    float docv = gate * xin[j] + (1.0f - gate) * xin[HD + j];
    ds[j] = docv;
    __syncthreads();

    acc = mb1[j];
    for (int k = 0; k < HD; ++k) acc = fmaf(ds[k], mW1[k * HD + j], acc);
    float u = gelu_f(acc);

    float s = u, q = u * u;
    #pragma unroll
    for (int o = 32; o > 0; o >>= 1) {
        s += __shfl_xor(s, o);
        q += __shfl_xor(q, o);
    }
    if (lane == 0) { rs[wave] = s; rq[wave] = q; }
    __syncthreads();
    if (j == 0) {
        float ss = 0.0f, qq = 0.0f;
        #pragma unroll
        for (int w = 0; w < 6; ++w) { ss += rs[w]; qq += rq[w]; }
        float m = ss * (1.0f / HD);
        mean_s = m;
        rstd_s = rsqrtf(qq * (1.0f / HD) - m * m + 1e-5f);
    }
    __syncthreads();
    float un = (u - mean_s) * rstd_s * mg[j] + mbn[j];
    t1[j] = un;
    __syncthreads();

    if (j < HHD) {
        acc = mb2[j];
        for (int k = 0; k < HD; ++k) acc = fmaf(t1[k], mW2[k * HHD + j], acc);
        vs[j] = gelu_f(acc);
    }
    __syncthreads();

    if (j < 2) {
        acc = cb[j];
        for (int k = 0; k < HHD; ++k) acc = fmaf(vs[k], cW[k * 2 + j], acc);
        out[(long long)d * 2 + j] = acc;
    }
}

static void build_csr(const int* rows, const int* cols, const float* vals,
                      int nnz, int n, int* rp, int* cp, float* vp,
                      int* cnt, int* bsum, int* boff, hipStream_t stream) {
    hipMemsetAsync(cnt, 0, (size_t)n * sizeof(int), stream);
    hist_rows<<<(nnz + 255) / 256, 256, 0, stream>>>(rows, cnt, nnz);
    int nb = (n + 255) / 256;
    scan_local<<<nb, 256, 0, stream>>>(cnt, rp, bsum, n);
    scan_bsums<<<1, 256, 0, stream>>>(bsum, boff, nb, rp + n);
    scan_add<<<nb, 256, 0, stream>>>(rp, boff, n);
    hipMemsetAsync(cnt, 0, (size_t)n * sizeof(int), stream);
    csr_scatter<<<(nnz + 255) / 256, 256, 0, stream>>>(rows, cols, vals, rp, cnt, cp, vp, nnz);
}

extern "C" void kernel_launch(void* const* d_in, const int* in_sizes, int n_in,
                              void* d_out, int out_size, void* d_ws, size_t ws_size,
                              hipStream_t stream) {
    const int*   A_rows = (const int*)  d_in[0];
    const int*   A_cols = (const int*)  d_in[1];
    const float* A_vals = (const float*)d_in[2];
    const int*   X_rows = (const int*)  d_in[3];
    const int*   X_cols = (const int*)  d_in[4];
    const float* X_vals = (const float*)d_in[5];
    const float* emb    = (const float*)d_in[7];
    const float* W1     = (const float*)d_in[8];
    const float* W2     = (const float*)d_in[9];
    const float* W3     = (const float*)d_in[10];
    const float* g1     = (const float*)d_in[11];
    const float* b1     = (const float*)d_in[12];
    const float* g2     = (const float*)d_in[13];
    const float* b2     = (const float*)d_in[14];
    const float* g3     = (const float*)d_in[15];
    const float* b3     = (const float*)d_in[16];
    const float* mW1    = (const float*)d_in[17];
    const float* mb1    = (const float*)d_in[18];
    const float* mg     = (const float*)d_in[19];
    const float* mbn    = (const float*)d_in[20];
    const float* mW2    = (const float*)d_in[21];
    const float* mb2    = (const float*)d_in[22];
    const float* cW     = (const float*)d_in[23];
    const float* cb     = (const float*)d_in[24];
    const float* gW1    = (const float*)d_in[25];
    const float* gb1    = (const float*)d_in[26];
    const float* gW2    = (const float*)d_in[27];
    const float* gb2    = (const float*)d_in[28];

    const int E_   = in_sizes[0];
    const int NNZ_ = in_sizes[3];
    const int N_   = in_sizes[7] / HD;
    const int D_   = out_size / 2;

    // ---- workspace layout ----
    float* buf1 = (float*)d_ws;                       // [N, H]
    float* buf2 = buf1 + (size_t)N_ * HD;             // [N, H]
    int*   A_rp = (int*)(buf2 + (size_t)N_ * HD);     // N+1
    int*   A_cp = A_rp + (N_ + 1);                    // E
    float* A_vp = (float*)(A_cp + E_);                // E
    int*   X_rp = (int*)(A_vp + E_);                  // D+1
    int*   X_cp = X_rp + (D_ + 1);                    // NNZ
    float* X_vp = (float*)(X_cp + NNZ_);              // NNZ
    int*   cnt  = (int*)(X_vp + NNZ_);                // max(N,D)
    int*   bsum = cnt + N_;                           // <=256
    int*   boff = bsum + 256;                         // <=256

    float* dbuf1 = buf2;                              // [D, H] after GCN done
    float* dbuf2 = buf2 + (size_t)D_ * HD;            // [D, H]
    float* logits = (float*)d_out;

    const int gemm_grid = (N_ + 7) / 8;
    const int n4 = N_ * HD / 4;

    // ---- build CSR for A (word graph) and X (tfidf) ----
    build_csr(A_rows, A_cols, A_vals, E_, N_, A_rp, A_cp, A_vp, cnt, bsum, boff, stream);
    build_csr(X_rows, X_cols, X_vals, NNZ_, D_, X_rp, X_cp, X_vp, cnt, bsum, boff, stream);

    // ---- GCN block 1 ----
    spmm_csr<<<N_, 384, 0, stream>>>(A_rp, A_cp, A_vp, emb, buf1, N_);
    gemm_ln_gelu<<<gemm_grid, 384, 0, stream>>>(buf1, W1, g1, b1, buf2, N_);
    // ---- GCN block 2 ----
    spmm_csr<<<N_, 384, 0, stream>>>(A_rp, A_cp, A_vp, buf2, buf1, N_);
    gemm_ln_gelu<<<gemm_grid, 384, 0, stream>>>(buf1, W2, g2, b2, buf2, N_);
    // ---- GCN block 3 ----
    spmm_csr<<<N_, 384, 0, stream>>>(A_rp, A_cp, A_vp, buf2, buf1, N_);
    gemm_ln_gelu<<<gemm_grid, 384, 0, stream>>>(buf1, W3, g3, b3, buf2, N_);

    // ---- word_H = 0.35*emb + 0.65*h  (into buf1) ----
    axpby_kernel<<<(n4 + 255) / 256, 256, 0, stream>>>(emb, buf2, buf1, n4);

    // ---- doc aggregation ----
    spmm_csr<<<D_, 384, 0, stream>>>(X_rp, X_cp, X_vp, buf1, dbuf1, D_);
    spmm_csr<<<D_, 384, 0, stream>>>(X_rp, X_cp, X_vp, emb, dbuf2, D_);

    // ---- fused doc head ----
    doc_head<<<D_, 384, 0, stream>>>(dbuf1, dbuf2,
                                     gW1, gb1, gW2, gb2,
                                     mW1, mb1, mg, mbn, mW2, mb2,
                                     cW, cb, logits, D_);
}

// Round 3
// 3313.416 us; speedup vs baseline: 6.9117x; 1.2610x over previous
//
#include <hip/hip_runtime.h>

#define HD 384
#define HHD 192

__device__ __forceinline__ float gelu_f(float x) {
    return 0.5f * x * (1.0f + erff(x * 0.70710678118654752f));
}

__device__ __forceinline__ float sigmoid_f(float x) {
    return 1.0f / (1.0f + expf(-x));
}

// ---------------- CSR build: histogram + scan + scatter ----------------
__global__ __launch_bounds__(256) void hist_rows(
        const int* __restrict__ rows, int* __restrict__ cnt, int nnz) {
    int e = blockIdx.x * blockDim.x + threadIdx.x;
    if (e < nnz) atomicAdd(&cnt[rows[e]], 1);
}

__global__ __launch_bounds__(256) void scan_local(
        const int* __restrict__ cnt, int* __restrict__ rp,
        int* __restrict__ bsum, int n) {
    __shared__ int wsum[4];
    int i = blockIdx.x * 256 + threadIdx.x;
    int lane = threadIdx.x & 63, wv = threadIdx.x >> 6;
    int v = (i < n) ? cnt[i] : 0;
    int s = v;
    #pragma unroll
    for (int o = 1; o < 64; o <<= 1) {
        int t = __shfl_up(s, o);
        if (lane >= o) s += t;
    }
    if (lane == 63) wsum[wv] = s;
    __syncthreads();
    int woff = 0;
    for (int w = 0; w < wv; ++w) woff += wsum[w];
    if (i < n) rp[i] = woff + s - v;
    if (threadIdx.x == 255) bsum[blockIdx.x] = woff + s;
}

__global__ __launch_bounds__(256) void scan_bsums(
        const int* __restrict__ bsum, int* __restrict__ boff,
        int nb, int* __restrict__ total_out) {
    __shared__ int tmp[256];
    int tid = threadIdx.x;
    int v = (tid < nb) ? bsum[tid] : 0;
    tmp[tid] = v;
    __syncthreads();
    for (int o = 1; o < 256; o <<= 1) {
        int t = (tid >= o) ? tmp[tid - o] : 0;
        __syncthreads();
        tmp[tid] += t;
        __syncthreads();
    }
    if (tid < nb) boff[tid] = tmp[tid] - v;
    if (tid == nb - 1) *total_out = tmp[tid];
}

__global__ __launch_bounds__(256) void scan_add(
        int* __restrict__ rp, const int* __restrict__ boff, int n) {
    int i = blockIdx.x * 256 + threadIdx.x;
    if (i < n) rp[i] += boff[i >> 8];
}

__global__ __launch_bounds__(256) void csr_scatter(
        const int* __restrict__ rows, const int* __restrict__ cols,
        const float* __restrict__ vals, const int* __restrict__ rp,
        int* __restrict__ fill, int* __restrict__ cp,
        float* __restrict__ vp, int nnz) {
    int e = blockIdx.x * blockDim.x + threadIdx.x;
    if (e >= nnz) return;
    int r = rows[e];
    int pos = rp[r] + atomicAdd(&fill[r], 1);
    cp[pos] = cols[e];
    vp[pos] = vals[e];
}

// ---------------- SpMM (CSR gather) ----------------
__global__ __launch_bounds__(384) void spmm_csr(
        const int* __restrict__ rp, const int* __restrict__ cp,
        const float* __restrict__ vp, const float* __restrict__ in,
        float* __restrict__ out, int nrows) {
    const int r = blockIdx.x;
    const int j = threadIdx.x;
    const int s = rp[r], e = rp[r + 1];
    float acc = 0.0f;
    for (int p = s; p < e; ++p) {
        int c = cp[p];
        float v = vp[p];
        acc = fmaf(v, in[(size_t)c * HD + j], acc);
    }
    out[(size_t)r * HD + j] = acc;
}

// ---------------- out = gelu(LN(in @ W, g, b)); 8 rows per block ----------------
__global__ __launch_bounds__(384) void gemm_ln_gelu(
        const float* __restrict__ in, const float* __restrict__ W,
        const float* __restrict__ g, const float* __restrict__ b,
        float* __restrict__ out, int nrows) {
    __shared__ float xs[8][HD];
    __shared__ float rs[6][8], rq[6][8];
    __shared__ float mean_s[8], rstd_s[8];
    const int j = threadIdx.x;
    const int row0 = blockIdx.x * 8;
    const int wave = j >> 6, lane = j & 63;

    #pragma unroll
    for (int r = 0; r < 8; ++r) {
        int row = row0 + r;
        xs[r][j] = (row < nrows) ? in[(long long)row * HD + j] : 0.0f;
    }
    __syncthreads();

    float acc[8];
    #pragma unroll
    for (int r = 0; r < 8; ++r) acc[r] = 0.0f;

    for (int k = 0; k < HD; k += 4) {
        float w0 = W[(k + 0) * HD + j];
        float w1 = W[(k + 1) * HD + j];
        float w2 = W[(k + 2) * HD + j];
        float w3 = W[(k + 3) * HD + j];
        #pragma unroll
        for (int r = 0; r < 8; ++r) {
            float4 x4 = *reinterpret_cast<const float4*>(&xs[r][k]);
            acc[r] = fmaf(x4.x, w0, acc[r]);
            acc[r] = fmaf(x4.y, w1, acc[r]);
            acc[r] = fmaf(x4.z, w2, acc[r]);
            acc[r] = fmaf(x4.w, w3, acc[r]);
        }
    }

    #pragma unroll
    for (int r = 0; r < 8; ++r) {
        float s = acc[r], q = acc[r] * acc[r];
        #pragma unroll
        for (int o = 32; o > 0; o >>= 1) {
            s += __shfl_xor(s, o);
            q += __shfl_xor(q, o);
        }
        if (lane == 0) { rs[wave][r] = s; rq[wave][r] = q; }
    }
    __syncthreads();
    if (j < 8) {
        float s = 0.0f, q = 0.0f;
        #pragma unroll
        for (int w = 0; w < 6; ++w) { s += rs[w][j]; q += rq[w][j]; }
        float m = s * (1.0f / HD);
        float v = q * (1.0f / HD) - m * m;
        mean_s[j] = m;
        rstd_s[j] = rsqrtf(v + 1e-5f);
    }
    __syncthreads();

    float gj = g[j], bj = b[j];
    #pragma unroll
    for (int r = 0; r < 8; ++r) {
        int row = row0 + r;
        if (row < nrows) {
            float y = (acc[r] - mean_s[r]) * rstd_s[r] * gj + bj;
            out[(long long)row * HD + j] = gelu_f(y);
        }
    }
}

// ---------------- word_H = 0.35*emb + 0.65*h ----------------
__global__ __launch_bounds__(256) void axpby_kernel(
        const float* __restrict__ a, const float* __restrict__ h,
        float* __restrict__ o, int n4) {
    int i = blockIdx.x * blockDim.x + threadIdx.x;
    if (i >= n4) return;
    float4 x = reinterpret_cast<const float4*>(a)[i];
    float4 y = reinterpret_cast<const float4*>(h)[i];
    float4 r;
    r.x = 0.35f * x.x + 0.65f * y.x;
    r.y = 0.35f * x.y + 0.65f * y.y;
    r.z = 0.35f * x.z + 0.65f * y.z;
    r.w = 0.35f * x.w + 0.65f * y.w;
    reinterpret_cast<float4*>(o)[i] = r;
}

// ---------------- gate_fused: 8 docs/block ----------------
// t1 = gelu([docH|docH0] @ gW1 + gb1); gate = sigmoid(t1 @ gW2 + gb2);
// dmix = gate*docH + (1-gate)*docH0
__global__ __launch_bounds__(384) void gate_fused(
        const float* __restrict__ docH, const float* __restrict__ docH0,
        const float* __restrict__ gW1, const float* __restrict__ gb1,
        const float* __restrict__ gW2, const float* __restrict__ gb2,
        float* __restrict__ dmix, int ndocs) {
    __shared__ float xin[8][2 * HD];
    __shared__ float t1[8][HD];
    const int j = threadIdx.x;
    const int row0 = blockIdx.x * 8;

    for (int t = j; t < 8 * 2 * HD; t += 384) {
        int r = t / (2 * HD), c = t % (2 * HD);
        int row = row0 + r;
        float v = 0.0f;
        if (row < ndocs)
            v = (c < HD) ? docH[(size_t)row * HD + c]
                         : docH0[(size_t)row * HD + (c - HD)];
        xin[r][c] = v;
    }
    __syncthreads();

    // gate1: K = 768
    float acc[8];
    {
        float bb = gb1[j];
        #pragma unroll
        for (int r = 0; r < 8; ++r) acc[r] = bb;
    }
    for (int k = 0; k < 2 * HD; k += 4) {
        float w0 = gW1[(k + 0) * HD + j];
        float w1 = gW1[(k + 1) * HD + j];
        float w2 = gW1[(k + 2) * HD + j];
        float w3 = gW1[(k + 3) * HD + j];
        #pragma unroll
        for (int r = 0; r < 8; ++r) {
            float4 x4 = *reinterpret_cast<const float4*>(&xin[r][k]);
            acc[r] = fmaf(x4.x, w0, acc[r]);
            acc[r] = fmaf(x4.y, w1, acc[r]);
            acc[r] = fmaf(x4.z, w2, acc[r]);
            acc[r] = fmaf(x4.w, w3, acc[r]);
        }
    }
    #pragma unroll
    for (int r = 0; r < 8; ++r) t1[r][j] = gelu_f(acc[r]);
    __syncthreads();

    // gate2: K = 384
    {
        float bb = gb2[j];
        #pragma unroll
        for (int r = 0; r < 8; ++r) acc[r] = bb;
    }
    for (int k = 0; k < HD; k += 4) {
        float w0 = gW2[(k + 0) * HD + j];
        float w1 = gW2[(k + 1) * HD + j];
        float w2 = gW2[(k + 2) * HD + j];
        float w3 = gW2[(k + 3) * HD + j];
        #pragma unroll
        for (int r = 0; r < 8; ++r) {
            float4 x4 = *reinterpret_cast<const float4*>(&t1[r][k]);
            acc[r] = fmaf(x4.x, w0, acc[r]);
            acc[r] = fmaf(x4.y, w1, acc[r]);
            acc[r] = fmaf(x4.z, w2, acc[r]);
            acc[r] = fmaf(x4.w, w3, acc[r]);
        }
    }
    #pragma unroll
    for (int r = 0; r < 8; ++r) {
        int row = row0 + r;
        if (row < ndocs) {
            float gate = sigmoid_f(acc[r]);
            float v = gate * xin[r][j] + (1.0f - gate) * xin[r][HD + j];
            dmix[(size_t)row * HD + j] = v;
        }
    }
}

// ---------------- mlp_fused: 8 docs/block ----------------
// un = LN(gelu(dmix @ mW1 + mb1)); v = gelu(un @ mW2 + mb2); logits = v @ cW + cb
__global__ __launch_bounds__(384) void mlp_fused(
        const float* __restrict__ dmix,
        const float* __restrict__ mW1, const float* __restrict__ mb1,
        const float* __restrict__ mg, const float* __restrict__ mbn,
        const float* __restrict__ mW2, const float* __restrict__ mb2,
        const float* __restrict__ cW, const float* __restrict__ cb,
        float* __restrict__ out, int ndocs) {
    __shared__ float xs[8][HD];
    __shared__ float un[8][HD];
    __shared__ float vs[8][HHD];
    __shared__ float rs[6][8], rq[6][8];
    __shared__ float mean_s[8], rstd_s[8];
    const int j = threadIdx.x;
    const int row0 = blockIdx.x * 8;
    const int wave = j >> 6, lane = j & 63;

    #pragma unroll
    for (int r = 0; r < 8; ++r) {
        int row = row0 + r;
        xs[r][j] = (row < ndocs) ? dmix[(size_t)row * HD + j] : 0.0f;
    }
    __syncthreads();

    // mlp1: K = 384
    float acc[8];
    {
        float bb = mb1[j];
        #pragma unroll
        for (int r = 0; r < 8; ++r) acc[r] = bb;
    }
    for (int k = 0; k < HD; k += 4) {
        float w0 = mW1[(k + 0) * HD + j];
        float w1 = mW1[(k + 1) * HD + j];
        float w2 = mW1[(k + 2) * HD + j];
        float w3 = mW1[(k + 3) * HD + j];
        #pragma unroll
        for (int r = 0; r < 8; ++r) {
            float4 x4 = *reinterpret_cast<const float4*>(&xs[r][k]);
            acc[r] = fmaf(x4.x, w0, acc[r]);
            acc[r] = fmaf(x4.y, w1, acc[r]);
            acc[r] = fmaf(x4.z, w2, acc[r]);
            acc[r] = fmaf(x4.w, w3, acc[r]);
        }
    }
    // gelu then LN stats
    #pragma unroll
    for (int r = 0; r < 8; ++r) acc[r] = gelu_f(acc[r]);
    #pragma unroll
    for (int r = 0; r < 8; ++r) {
        float s = acc[r], q = acc[r] * acc[r];
        #pragma unroll
        for (int o = 32; o > 0; o >>= 1) {
            s += __shfl_xor(s, o);
            q += __shfl_xor(q, o);
        }
        if (lane == 0) { rs[wave][r] = s; rq[wave][r] = q; }
    }
    __syncthreads();
    if (j < 8) {
        float s = 0.0f, q = 0.0f;
        #pragma unroll
        for (int w = 0; w < 6; ++w) { s += rs[w][j]; q += rq[w][j]; }
        float m = s * (1.0f / HD);
        float v = q * (1.0f / HD) - m * m;
        mean_s[j] = m;
        rstd_s[j] = rsqrtf(v + 1e-5f);
    }
    __syncthreads();
    {
        float gj = mg[j], bj = mbn[j];
        #pragma unroll
        for (int r = 0; r < 8; ++r)
            un[r][j] = (acc[r] - mean_s[r]) * rstd_s[r] * gj + bj;
    }
    __syncthreads();

    // mlp2: K = 384, 192 out cols. 384 threads = 192 cols x 2 row-halves.
    {
        const int c = j % HHD;
        const int rbase = (j / HHD) * 4;
        float a4[4];
        float bb = mb2[c];
        #pragma unroll
        for (int r = 0; r < 4; ++r) a4[r] = bb;
        for (int k = 0; k < HD; k += 4) {
            float w0 = mW2[(k + 0) * HHD + c];
            float w1 = mW2[(k + 1) * HHD + c];
            float w2 = mW2[(k + 2) * HHD + c];
            float w3 = mW2[(k + 3) * HHD + c];
            #pragma unroll
            for (int r = 0; r < 4; ++r) {
                float4 x4 = *reinterpret_cast<const float4*>(&un[rbase + r][k]);
                a4[r] = fmaf(x4.x, w0, a4[r]);
                a4[r] = fmaf(x4.y, w1, a4[r]);
                a4[r] = fmaf(x4.z, w2, a4[r]);
                a4[r] = fmaf(x4.w, w3, a4[r]);
            }
        }
        #pragma unroll
        for (int r = 0; r < 4; ++r) vs[rbase + r][c] = gelu_f(a4[r]);
    }
    __syncthreads();

    // classifier: 16 outputs (8 rows x 2 cols)
    if (j < 16) {
        int r = j >> 1, c = j & 1;
        int row = row0 + r;
        if (row < ndocs) {
            float a = cb[c];
            for (int k = 0; k < HHD; ++k)
                a = fmaf(vs[r][k], cW[k * 2 + c], a);
            out[(size_t)row * 2 + c] = a;
        }
    }
}

static void build_csr(const int* rows, const int* cols, const float* vals,
                      int nnz, int n, int* rp, int* cp, float* vp,
                      int* cnt, int* bsum, int* boff, hipStream_t stream) {
    hipMemsetAsync(cnt, 0, (size_t)n * sizeof(int), stream);
    hist_rows<<<(nnz + 255) / 256, 256, 0, stream>>>(rows, cnt, nnz);
    int nb = (n + 255) / 256;
    scan_local<<<nb, 256, 0, stream>>>(cnt, rp, bsum, n);
    scan_bsums<<<1, 256, 0, stream>>>(bsum, boff, nb, rp + n);
    scan_add<<<nb, 256, 0, stream>>>(rp, boff, n);
    hipMemsetAsync(cnt, 0, (size_t)n * sizeof(int), stream);
    csr_scatter<<<(nnz + 255) / 256, 256, 0, stream>>>(rows, cols, vals, rp, cnt, cp, vp, nnz);
}

extern "C" void kernel_launch(void* const* d_in, const int* in_sizes, int n_in,
                              void* d_out, int out_size, void* d_ws, size_t ws_size,
                              hipStream_t stream) {
    const int*   A_rows = (const int*)  d_in[0];
    const int*   A_cols = (const int*)  d_in[1];
    const float* A_vals = (const float*)d_in[2];
    const int*   X_rows = (const int*)  d_in[3];
    const int*   X_cols = (const int*)  d_in[4];
    const float* X_vals = (const float*)d_in[5];
    const float* emb    = (const float*)d_in[7];
    const float* W1     = (const float*)d_in[8];
    const float* W2     = (const float*)d_in[9];
    const float* W3     = (const float*)d_in[10];
    const float* g1     = (const float*)d_in[11];
    const float* b1     = (const float*)d_in[12];
    const float* g2     = (const float*)d_in[13];
    const float* b2     = (const float*)d_in[14];
    const float* g3     = (const float*)d_in[15];
    const float* b3     = (const float*)d_in[16];
    const float* mW1    = (const float*)d_in[17];
    const float* mb1    = (const float*)d_in[18];
    const float* mg     = (const float*)d_in[19];
    const float* mbn    = (const float*)d_in[20];
    const float* mW2    = (const float*)d_in[21];
    const float* mb2    = (const float*)d_in[22];
    const float* cW     = (const float*)d_in[23];
    const float* cb     = (const float*)d_in[24];
    const float* gW1    = (const float*)d_in[25];
    const float* gb1    = (const float*)d_in[26];
    const float* gW2    = (const float*)d_in[27];
    const float* gb2    = (const float*)d_in[28];

    const int E_   = in_sizes[0];
    const int NNZ_ = in_sizes[3];
    const int N_   = in_sizes[7] / HD;
    const int D_   = out_size / 2;

    float* buf1 = (float*)d_ws;                       // [N, H]
    float* buf2 = buf1 + (size_t)N_ * HD;             // [N, H]
    int*   A_rp = (int*)(buf2 + (size_t)N_ * HD);
    int*   A_cp = A_rp + (N_ + 1);
    float* A_vp = (float*)(A_cp + E_);
    int*   X_rp = (int*)(A_vp + E_);
    int*   X_cp = X_rp + (D_ + 1);
    float* X_vp = (float*)(X_cp + NNZ_);
    int*   cnt  = (int*)(X_vp + NNZ_);
    int*   bsum = cnt + N_;
    int*   boff = bsum + 256;

    float* dbuf1 = buf2;                              // [D, H]
    float* dbuf2 = buf2 + (size_t)D_ * HD;            // [D, H]
    float* logits = (float*)d_out;

    const int gemm_grid = (N_ + 7) / 8;
    const int doc_grid = (D_ + 7) / 8;
    const int n4 = N_ * HD / 4;

    build_csr(A_rows, A_cols, A_vals, E_, N_, A_rp, A_cp, A_vp, cnt, bsum, boff, stream);
    build_csr(X_rows, X_cols, X_vals, NNZ_, D_, X_rp, X_cp, X_vp, cnt, bsum, boff, stream);

    // ---- GCN blocks ----
    spmm_csr<<<N_, 384, 0, stream>>>(A_rp, A_cp, A_vp, emb, buf1, N_);
    gemm_ln_gelu<<<gemm_grid, 384, 0, stream>>>(buf1, W1, g1, b1, buf2, N_);
    spmm_csr<<<N_, 384, 0, stream>>>(A_rp, A_cp, A_vp, buf2, buf1, N_);
    gemm_ln_gelu<<<gemm_grid, 384, 0, stream>>>(buf1, W2, g2, b2, buf2, N_);
    spmm_csr<<<N_, 384, 0, stream>>>(A_rp, A_cp, A_vp, buf2, buf1, N_);
    gemm_ln_gelu<<<gemm_grid, 384, 0, stream>>>(buf1, W3, g3, b3, buf2, N_);

    // ---- word_H into buf1 ----
    axpby_kernel<<<(n4 + 255) / 256, 256, 0, stream>>>(emb, buf2, buf1, n4);

    // ---- doc aggregation ----
    spmm_csr<<<D_, 384, 0, stream>>>(X_rp, X_cp, X_vp, buf1, dbuf1, D_);
    spmm_csr<<<D_, 384, 0, stream>>>(X_rp, X_cp, X_vp, emb, dbuf2, D_);

    // ---- doc head: gate then MLP (dmix overwrites buf1; word_H no longer needed) ----
    float* dmix = buf1;
    gate_fused<<<doc_grid, 384, 0, stream>>>(dbuf1, dbuf2, gW1, gb1, gW2, gb2, dmix, D_);
    mlp_fused<<<doc_grid, 384, 0, stream>>>(dmix, mW1, mb1, mg, mbn, mW2, mb2,
                                            cW, cb, logits, D_);
}

// Round 4
// 2900.812 us; speedup vs baseline: 7.8948x; 1.1422x over previous
//
#include <hip/hip_runtime.h>

#define HD 384
#define HHD 192

using bf16x8 = __attribute__((ext_vector_type(8))) short;
using f32x4  = __attribute__((ext_vector_type(4))) float;

__device__ __forceinline__ float gelu_f(float x) {
    return 0.5f * x * (1.0f + erff(x * 0.70710678118654752f));
}

__device__ __forceinline__ float sigmoid_f(float x) {
    return 1.0f / (1.0f + expf(-x));
}

// ---------------- CSR build: histogram + scan + scatter ----------------
__global__ __launch_bounds__(256) void hist_rows(
        const int* __restrict__ rows, int* __restrict__ cnt, int nnz) {
    int e = blockIdx.x * blockDim.x + threadIdx.x;
    if (e < nnz) atomicAdd(&cnt[rows[e]], 1);
}

__global__ __launch_bounds__(256) void scan_local(
        const int* __restrict__ cnt, int* __restrict__ rp,
        int* __restrict__ bsum, int n) {
    __shared__ int wsum[4];
    int i = blockIdx.x * 256 + threadIdx.x;
    int lane = threadIdx.x & 63, wv = threadIdx.x >> 6;
    int v = (i < n) ? cnt[i] : 0;
    int s = v;
    #pragma unroll
    for (int o = 1; o < 64; o <<= 1) {
        int t = __shfl_up(s, o);
        if (lane >= o) s += t;
    }
    if (lane == 63) wsum[wv] = s;
    __syncthreads();
    int woff = 0;
    for (int w = 0; w < wv; ++w) woff += wsum[w];
    if (i < n) rp[i] = woff + s - v;
    if (threadIdx.x == 255) bsum[blockIdx.x] = woff + s;
}

__global__ __launch_bounds__(256) void scan_bsums(
        const int* __restrict__ bsum, int* __restrict__ boff,
        int nb, int* __restrict__ total_out) {
    __shared__ int tmp[256];
    int tid = threadIdx.x;
    int v = (tid < nb) ? bsum[tid] : 0;
    tmp[tid] = v;
    __syncthreads();
    for (int o = 1; o < 256; o <<= 1) {
        int t = (tid >= o) ? tmp[tid - o] : 0;
        __syncthreads();
        tmp[tid] += t;
        __syncthreads();
    }
    if (tid < nb) boff[tid] = tmp[tid] - v;
    if (tid == nb - 1) *total_out = tmp[tid];
}

__global__ __launch_bounds__(256) void scan_add(
        int* __restrict__ rp, const int* __restrict__ boff, int n) {
    int i = blockIdx.x * 256 + threadIdx.x;
    if (i < n) rp[i] += boff[i >> 8];
}

__global__ __launch_bounds__(256) void csr_scatter(
        const int* __restrict__ rows, const int* __restrict__ cols,
        const float* __restrict__ vals, const int* __restrict__ rp,
        int* __restrict__ fill, int* __restrict__ cp,
        float* __restrict__ vp, int nnz) {
    int e = blockIdx.x * blockDim.x + threadIdx.x;
    if (e >= nnz) return;
    int r = rows[e];
    int pos = rp[r] + atomicAdd(&fill[r], 1);
    cp[pos] = cols[e];
    vp[pos] = vals[e];
}

// ---------------- SpMM (CSR gather) ----------------
__global__ __launch_bounds__(384) void spmm_csr(
        const int* __restrict__ rp, const int* __restrict__ cp,
        const float* __restrict__ vp, const float* __restrict__ in,
        float* __restrict__ out, int nrows) {
    const int r = blockIdx.x;
    const int j = threadIdx.x;
    const int s = rp[r], e = rp[r + 1];
    float acc = 0.0f;
    for (int p = s; p < e; ++p) {
        int c = cp[p];
        float v = vp[p];
        acc = fmaf(v, in[(size_t)c * HD + j], acc);
    }
    out[(size_t)r * HD + j] = acc;
}

// ---------------- word_H = 0.35*emb + 0.65*h ----------------
__global__ __launch_bounds__(256) void axpby_kernel(
        const float* __restrict__ a, const float* __restrict__ h,
        float* __restrict__ o, int n4) {
    int i = blockIdx.x * blockDim.x + threadIdx.x;
    if (i >= n4) return;
    float4 x = reinterpret_cast<const float4*>(a)[i];
    float4 y = reinterpret_cast<const float4*>(h)[i];
    float4 r;
    r.x = 0.35f * x.x + 0.65f * y.x;
    r.y = 0.35f * x.y + 0.65f * y.y;
    r.z = 0.35f * x.z + 0.65f * y.z;
    r.w = 0.35f * x.w + 0.65f * y.w;
    reinterpret_cast<float4*>(o)[i] = r;
}

// ---------------- weight pack: fp32 [K,N] -> fragment-layout hi/lo bf16 ----------------
// layout: plane(0=hi,1=lo) [KS][NS][64 lanes][8 elems], elem e of lane l at kstep ks,
// nsub ns holds W[32*ks + 8*(l>>4) + e][ns*16 + (l&15)]
__global__ __launch_bounds__(256) void pack_w(
        const float* __restrict__ W, unsigned short* __restrict__ out,
        int KS, int NS, int N) {
    int t = blockIdx.x * 256 + threadIdx.x;
    int total = KS * NS * 64;
    if (t >= total) return;
    int l = t & 63;
    int ns = (t >> 6) % NS;
    int ks = t / (64 * NS);
    int col = ns * 16 + (l & 15);
    int k0 = ks * 32 + 8 * (l >> 4);
    size_t obase = (size_t)t * 8;
    size_t pstride = (size_t)KS * NS * 512;
    #pragma unroll
    for (int e = 0; e < 8; ++e) {
        float f = W[(size_t)(k0 + e) * N + col];
        unsigned u = __float_as_uint(f);
        unsigned short h = (unsigned short)(u >> 16);
        float r = f - __uint_as_float(u & 0xFFFF0000u);
        unsigned short lo = (unsigned short)(__float_as_uint(r) >> 16);
        out[obase + e] = (unsigned short)h;
        out[pstride + obase + e] = lo;
    }
}

__device__ __forceinline__ void split8(float4 a, float4 b, bf16x8& h, bf16x8& l) {
    float f[8] = {a.x, a.y, a.z, a.w, b.x, b.y, b.z, b.w};
    #pragma unroll
    for (int e = 0; e < 8; ++e) {
        unsigned u = __float_as_uint(f[e]);
        h[e] = (short)(unsigned short)(u >> 16);
        float r = f[e] - __uint_as_float(u & 0xFFFF0000u);
        l[e] = (short)(unsigned short)(__float_as_uint(r) >> 16);
    }
}

// ---------------- unified split-bf16 MFMA GEMM with fused epilogues ----------------
// MODE 0: out = gelu(LN(A@W, gamma, beta))                       (word GCN)
// MODE 1: out = gelu(A@W + bias)                                 (gate1; A=[A1|A2])
// MODE 2: g = sigmoid(A@W + bias); out = g*aux1 + (1-g)*aux2     (gate2 + mix)
// MODE 3: out = LN(gelu(A@W + bias), gamma, beta)                (mlp1)
// MODE 4: v = gelu(A@W + bias); out = v @ aux1 + gamma           (mlp2 + classifier)
template<int MODE, int NS, int KS, int KSPLIT>
__global__ __launch_bounds__(256) void gemm_mfma(
        const float* __restrict__ A1, const float* __restrict__ A2,
        const unsigned short* __restrict__ Wp,
        const float* __restrict__ bias, const float* __restrict__ gamma,
        const float* __restrict__ beta,
        const float* __restrict__ aux1, const float* __restrict__ aux2,
        float* __restrict__ out, int M) {
    constexpr int N = NS * 16;
    const int tid = threadIdx.x;
    const int wave = tid >> 6, l = tid & 63;
    const int row_base = blockIdx.x * 64 + wave * 16;
    const int arow = row_base + (l & 15);
    const bool arow_ok = arow < M;
    const int koff = 8 * (l >> 4);
    const size_t pstride = (size_t)KS * NS * 512;

    f32x4 acc[NS];
    #pragma unroll
    for (int ns = 0; ns < NS; ++ns)
        acc[ns] = f32x4{0.f, 0.f, 0.f, 0.f};

    for (int ks = 0; ks < KS; ++ks) {
        const float* Ap;
        int ksl;
        if (ks < KSPLIT) { Ap = A1; ksl = ks; }
        else             { Ap = A2; ksl = ks - KSPLIT; }
        bf16x8 ah, al;
        if (arow_ok) {
            const float* src = Ap + (size_t)arow * HD + ksl * 32 + koff;
            float4 a0 = *reinterpret_cast<const float4*>(src);
            float4 a1 = *reinterpret_cast<const float4*>(src + 4);
            split8(a0, a1, ah, al);
        } else {
            #pragma unroll
            for (int e = 0; e < 8; ++e) { ah[e] = 0; al[e] = 0; }
        }
        const unsigned short* Bp = Wp + (size_t)ks * NS * 512 + (size_t)l * 8;
        #pragma unroll
        for (int ns = 0; ns < NS; ++ns) {
            bf16x8 bh = *reinterpret_cast<const bf16x8*>(Bp + ns * 512);
            bf16x8 bl = *reinterpret_cast<const bf16x8*>(Bp + pstride + ns * 512);
            acc[ns] = __builtin_amdgcn_mfma_f32_16x16x32_bf16(ah, bh, acc[ns], 0, 0, 0);
            acc[ns] = __builtin_amdgcn_mfma_f32_16x16x32_bf16(al, bh, acc[ns], 0, 0, 0);
            acc[ns] = __builtin_amdgcn_mfma_f32_16x16x32_bf16(ah, bl, acc[ns], 0, 0, 0);
        }
    }

    // D layout: row = row_base + (l>>4)*4 + r, col = ns*16 + (l&15)
    const int col_lane = l & 15;
    const int r0 = row_base + (l >> 4) * 4;
    constexpr float invN = 1.0f / (float)N;

    if constexpr (MODE == 0 || MODE == 3) {
        if constexpr (MODE == 3) {
            // u = gelu(acc + bias) first
            #pragma unroll
            for (int ns = 0; ns < NS; ++ns) {
                float bb = bias[ns * 16 + col_lane];
                #pragma unroll
                for (int r = 0; r < 4; ++r)
                    acc[ns][r] = gelu_f(acc[ns][r] + bb);
            }
        }
        float s[4] = {0.f, 0.f, 0.f, 0.f}, q[4] = {0.f, 0.f, 0.f, 0.f};
        #pragma unroll
        for (int ns = 0; ns < NS; ++ns)
            #pragma unroll
            for (int r = 0; r < 4; ++r) {
                float v = acc[ns][r];
                s[r] += v;
                q[r] += v * v;
            }
        #pragma unroll
        for (int r = 0; r < 4; ++r) {
            #pragma unroll
            for (int m = 1; m < 16; m <<= 1) {
                s[r] += __shfl_xor(s[r], m);
                q[r] += __shfl_xor(q[r], m);
            }
        }
        float mean[4], rstd[4];
        #pragma unroll
        for (int r = 0; r < 4; ++r) {
            mean[r] = s[r] * invN;
            rstd[r] = rsqrtf(q[r] * invN - mean[r] * mean[r] + 1e-5f);
        }
        #pragma unroll
        for (int ns = 0; ns < NS; ++ns) {
            int col = ns * 16 + col_lane;
            float gg = gamma[col], bb = beta[col];
            #pragma unroll
            for (int r = 0; r < 4; ++r) {
                int row = r0 + r;
                if (row < M) {
                    float y = (acc[ns][r] - mean[r]) * rstd[r] * gg + bb;
                    if constexpr (MODE == 0) y = gelu_f(y);
                    out[(size_t)row * N + col] = y;
                }
            }
        }
    } else if constexpr (MODE == 1) {
        #pragma unroll
        for (int ns = 0; ns < NS; ++ns) {
            int col = ns * 16 + col_lane;
            float bb = bias[col];
            #pragma unroll
            for (int r = 0; r < 4; ++r) {
                int row = r0 + r;
                if (row < M)
                    out[(size_t)row * N + col] = gelu_f(acc[ns][r] + bb);
            }
        }
    } else if constexpr (MODE == 2) {
        #pragma unroll
        for (int ns = 0; ns < NS; ++ns) {
            int col = ns * 16 + col_lane;
            float bb = bias[col];
            #pragma unroll
            for (int r = 0; r < 4; ++r) {
                int row = r0 + r;
                if (row < M) {
                    float g = sigmoid_f(acc[ns][r] + bb);
                    float h1 = aux1[(size_t)row * N + col];
                    float h0 = aux2[(size_t)row * N + col];
                    out[(size_t)row * N + col] = g * h1 + (1.0f - g) * h0;
                }
            }
        }
    } else if constexpr (MODE == 4) {
        float lg0[4] = {0.f, 0.f, 0.f, 0.f}, lg1[4] = {0.f, 0.f, 0.f, 0.f};
        #pragma unroll
        for (int ns = 0; ns < NS; ++ns) {
            int col = ns * 16 + col_lane;
            float bb = bias[col];
            float c0 = aux1[col * 2 + 0];
            float c1 = aux1[col * 2 + 1];
            #pragma unroll
            for (int r = 0; r < 4; ++r) {
                float v = gelu_f(acc[ns][r] + bb);
                lg0[r] = fmaf(v, c0, lg0[r]);
                lg1[r] = fmaf(v, c1, lg1[r]);
            }
        }
        #pragma unroll
        for (int r = 0; r < 4; ++r) {
            #pragma unroll
            for (int m = 1; m < 16; m <<= 1) {
                lg0[r] += __shfl_xor(lg0[r], m);
                lg1[r] += __shfl_xor(lg1[r], m);
            }
        }
        if (col_lane == 0) {
            float cb0 = gamma[0], cb1 = gamma[1];
            #pragma unroll
            for (int r = 0; r < 4; ++r) {
                int row = r0 + r;
                if (row < M) {
                    out[(size_t)row * 2 + 0] = lg0[r] + cb0;
                    out[(size_t)row * 2 + 1] = lg1[r] + cb1;
                }
            }
        }
    }
}

static void build_csr(const int* rows, const int* cols, const float* vals,
                      int nnz, int n, int* rp, int* cp, float* vp,
                      int* cnt, int* bsum, int* boff, hipStream_t stream) {
    hipMemsetAsync(cnt, 0, (size_t)n * sizeof(int), stream);
    hist_rows<<<(nnz + 255) / 256, 256, 0, stream>>>(rows, cnt, nnz);
    int nb = (n + 255) / 256;
    scan_local<<<nb, 256, 0, stream>>>(cnt, rp, bsum, n);
    scan_bsums<<<1, 256, 0, stream>>>(bsum, boff, nb, rp + n);
    scan_add<<<nb, 256, 0, stream>>>(rp, boff, n);
    hipMemsetAsync(cnt, 0, (size_t)n * sizeof(int), stream);
    csr_scatter<<<(nnz + 255) / 256, 256, 0, stream>>>(rows, cols, vals, rp, cnt, cp, vp, nnz);
}

extern "C" void kernel_launch(void* const* d_in, const int* in_sizes, int n_in,
                              void* d_out, int out_size, void* d_ws, size_t ws_size,
                              hipStream_t stream) {
    const int*   A_rows = (const int*)  d_in[0];
    const int*   A_cols = (const int*)  d_in[1];
    const float* A_vals = (const float*)d_in[2];
    const int*   X_rows = (const int*)  d_in[3];
    const int*   X_cols = (const int*)  d_in[4];
    const float* X_vals = (const float*)d_in[5];
    const float* emb    = (const float*)d_in[7];
    const float* W1     = (const float*)d_in[8];
    const float* W2     = (const float*)d_in[9];
    const float* W3     = (const float*)d_in[10];
    const float* g1     = (const float*)d_in[11];
    const float* b1     = (const float*)d_in[12];
    const float* g2     = (const float*)d_in[13];
    const float* b2     = (const float*)d_in[14];
    const float* g3     = (const float*)d_in[15];
    const float* b3     = (const float*)d_in[16];
    const float* mW1    = (const float*)d_in[17];
    const float* mb1    = (const float*)d_in[18];
    const float* mg     = (const float*)d_in[19];
    const float* mbn    = (const float*)d_in[20];
    const float* mW2    = (const float*)d_in[21];
    const float* mb2    = (const float*)d_in[22];
    const float* cW     = (const float*)d_in[23];
    const float* cb     = (const float*)d_in[24];
    const float* gW1    = (const float*)d_in[25];
    const float* gb1    = (const float*)d_in[26];
    const float* gW2    = (const float*)d_in[27];
    const float* gb2    = (const float*)d_in[28];

    const int E_   = in_sizes[0];
    const int NNZ_ = in_sizes[3];
    const int N_   = in_sizes[7] / HD;
    const int D_   = out_size / 2;

    // ---- workspace layout (floats) ----
    float* buf1 = (float*)d_ws;                       // [N, H]
    float* buf2 = buf1 + (size_t)N_ * HD;             // [N, H]
    int*   A_rp = (int*)(buf2 + (size_t)N_ * HD);
    int*   A_cp = A_rp + (N_ + 1);
    float* A_vp = (float*)(A_cp + E_);
    int*   X_rp = (int*)(A_vp + E_);
    int*   X_cp = X_rp + (D_ + 1);
    float* X_vp = (float*)(X_cp + NNZ_);
    int*   cnt  = (int*)(X_vp + NNZ_);
    int*   bsum = cnt + N_;
    int*   boff = bsum + 256;
    // packs (align to 16B)
    size_t pk_off = ((size_t)(boff + 256 - (int*)d_ws) + 7) & ~(size_t)7;
    unsigned short* packs = (unsigned short*)((float*)d_ws + pk_off);
    const size_t SZ_SQ = (size_t)2 * HD * HD;         // 294912 ushorts (384x384 hi+lo)
    unsigned short* p_W1  = packs;
    unsigned short* p_W2  = p_W1  + SZ_SQ;
    unsigned short* p_W3  = p_W2  + SZ_SQ;
    unsigned short* p_gW2 = p_W3  + SZ_SQ;
    unsigned short* p_mW1 = p_gW2 + SZ_SQ;
    unsigned short* p_gW1 = p_mW1 + SZ_SQ;            // 2*768*384
    unsigned short* p_mW2 = p_gW1 + (size_t)2 * 2 * HD * HD; // 2*384*192

    float* dbuf1 = buf2;                              // [D, H] docH
    float* dbuf2 = buf2 + (size_t)D_ * HD;            // [D, H] docH0
    float* t1    = buf1;                              // [D, H] (word_H dead by then)
    float* dmix  = buf1 + (size_t)D_ * HD;            // [D, H]
    float* un    = buf1;                              // [D, H] (t1 dead by then)
    float* logits = (float*)d_out;

    const int word_grid = (N_ + 63) / 64;             // 625
    const int doc_grid  = (D_ + 63) / 64;             // 313
    const int n4 = N_ * HD / 4;

    // ---- pack weights into MFMA fragment layout (hi/lo bf16) ----
    pack_w<<<(12 * 24 * 64 + 255) / 256, 256, 0, stream>>>(W1,  p_W1,  12, 24, HD);
    pack_w<<<(12 * 24 * 64 + 255) / 256, 256, 0, stream>>>(W2,  p_W2,  12, 24, HD);
    pack_w<<<(12 * 24 * 64 + 255) / 256, 256, 0, stream>>>(W3,  p_W3,  12, 24, HD);
    pack_w<<<(12 * 24 * 64 + 255) / 256, 256, 0, stream>>>(gW2, p_gW2, 12, 24, HD);
    pack_w<<<(12 * 24 * 64 + 255) / 256, 256, 0, stream>>>(mW1, p_mW1, 12, 24, HD);
    pack_w<<<(24 * 24 * 64 + 255) / 256, 256, 0, stream>>>(gW1, p_gW1, 24, 24, HD);
    pack_w<<<(12 * 12 * 64 + 255) / 256, 256, 0, stream>>>(mW2, p_mW2, 12, 12, HHD);

    // ---- build CSR ----
    build_csr(A_rows, A_cols, A_vals, E_, N_, A_rp, A_cp, A_vp, cnt, bsum, boff, stream);
    build_csr(X_rows, X_cols, X_vals, NNZ_, D_, X_rp, X_cp, X_vp, cnt, bsum, boff, stream);

    // ---- GCN blocks: spmm -> MFMA GEMM + LN + gelu ----
    spmm_csr<<<N_, 384, 0, stream>>>(A_rp, A_cp, A_vp, emb, buf1, N_);
    gemm_mfma<0, 24, 12, 12><<<word_grid, 256, 0, stream>>>(
        buf1, nullptr, p_W1, nullptr, g1, b1, nullptr, nullptr, buf2, N_);
    spmm_csr<<<N_, 384, 0, stream>>>(A_rp, A_cp, A_vp, buf2, buf1, N_);
    gemm_mfma<0, 24, 12, 12><<<word_grid, 256, 0, stream>>>(
        buf1, nullptr, p_W2, nullptr, g2, b2, nullptr, nullptr, buf2, N_);
    spmm_csr<<<N_, 384, 0, stream>>>(A_rp, A_cp, A_vp, buf2, buf1, N_);
    gemm_mfma<0, 24, 12, 12><<<word_grid, 256, 0, stream>>>(
        buf1, nullptr, p_W3, nullptr, g3, b3, nullptr, nullptr, buf2, N_);

    // ---- word_H into buf1 ----
    axpby_kernel<<<(n4 + 255) / 256, 256, 0, stream>>>(emb, buf2, buf1, n4);

    // ---- doc aggregation (dbuf overwrites buf2; h dead) ----
    spmm_csr<<<D_, 384, 0, stream>>>(X_rp, X_cp, X_vp, buf1, dbuf1, D_);
    spmm_csr<<<D_, 384, 0, stream>>>(X_rp, X_cp, X_vp, emb, dbuf2, D_);

    // ---- doc head ----
    // gate1: t1 = gelu([docH|docH0] @ gW1 + gb1)   (t1 over word_H region)
    gemm_mfma<1, 24, 24, 12><<<doc_grid, 256, 0, stream>>>(
        dbuf1, dbuf2, p_gW1, gb1, nullptr, nullptr, nullptr, nullptr, t1, D_);
    // gate2 + mix: dmix = sig(t1@gW2+gb2)*docH + (1-sig)*docH0
    gemm_mfma<2, 24, 12, 12><<<doc_grid, 256, 0, stream>>>(
        t1, nullptr, p_gW2, gb2, nullptr, nullptr, dbuf1, dbuf2, dmix, D_);
    // mlp1: un = LN(gelu(dmix@mW1+mb1), mg, mbn)
    gemm_mfma<3, 24, 12, 12><<<doc_grid, 256, 0, stream>>>(
        dmix, nullptr, p_mW1, mb1, mg, mbn, nullptr, nullptr, un, D_);
    // mlp2 + classifier: logits = gelu(un@mW2+mb2) @ cW + cb
    gemm_mfma<4, 12, 12, 12><<<doc_grid, 256, 0, stream>>>(
        un, nullptr, p_mW2, mb2, cb, nullptr, cW, nullptr, logits, D_);
}

// Round 5
// 2102.124 us; speedup vs baseline: 10.8943x; 1.3799x over previous
//
#include <hip/hip_runtime.h>

#define HD 384
#define HHD 192

using bf16x8 = __attribute__((ext_vector_type(8))) short;
using f32x4  = __attribute__((ext_vector_type(4))) float;

__device__ __forceinline__ float gelu_f(float x) {
    return 0.5f * x * (1.0f + erff(x * 0.70710678118654752f));
}

__device__ __forceinline__ float sigmoid_f(float x) {
    return 1.0f / (1.0f + expf(-x));
}

// ---------------- CSR build: histogram + scan + scatter ----------------
__global__ __launch_bounds__(256) void hist_rows(
        const int* __restrict__ rows, int* __restrict__ cnt, int nnz) {
    int e = blockIdx.x * blockDim.x + threadIdx.x;
    if (e < nnz) atomicAdd(&cnt[rows[e]], 1);
}

__global__ __launch_bounds__(256) void scan_local(
        const int* __restrict__ cnt, int* __restrict__ rp,
        int* __restrict__ bsum, int n) {
    __shared__ int wsum[4];
    int i = blockIdx.x * 256 + threadIdx.x;
    int lane = threadIdx.x & 63, wv = threadIdx.x >> 6;
    int v = (i < n) ? cnt[i] : 0;
    int s = v;
    #pragma unroll
    for (int o = 1; o < 64; o <<= 1) {
        int t = __shfl_up(s, o);
        if (lane >= o) s += t;
    }
    if (lane == 63) wsum[wv] = s;
    __syncthreads();
    int woff = 0;
    for (int w = 0; w < wv; ++w) woff += wsum[w];
    if (i < n) rp[i] = woff + s - v;
    if (threadIdx.x == 255) bsum[blockIdx.x] = woff + s;
}

__global__ __launch_bounds__(256) void scan_bsums(
        const int* __restrict__ bsum, int* __restrict__ boff,
        int nb, int* __restrict__ total_out) {
    __shared__ int tmp[256];
    int tid = threadIdx.x;
    int v = (tid < nb) ? bsum[tid] : 0;
    tmp[tid] = v;
    __syncthreads();
    for (int o = 1; o < 256; o <<= 1) {
        int t = (tid >= o) ? tmp[tid - o] : 0;
        __syncthreads();
        tmp[tid] += t;
        __syncthreads();
    }
    if (tid < nb) boff[tid] = tmp[tid] - v;
    if (tid == nb - 1) *total_out = tmp[tid];
}

__global__ __launch_bounds__(256) void scan_add(
        int* __restrict__ rp, const int* __restrict__ boff, int n) {
    int i = blockIdx.x * 256 + threadIdx.x;
    if (i < n) rp[i] += boff[i >> 8];
}

__global__ __launch_bounds__(256) void csr_scatter(
        const int* __restrict__ rows, const int* __restrict__ cols,
        const float* __restrict__ vals, const int* __restrict__ rp,
        int* __restrict__ fill, int* __restrict__ cp,
        float* __restrict__ vp, int nnz) {
    int e = blockIdx.x * blockDim.x + threadIdx.x;
    if (e >= nnz) return;
    int r = rows[e];
    int pos = rp[r] + atomicAdd(&fill[r], 1);
    cp[pos] = cols[e];
    vp[pos] = vals[e];
}

// ---------------- SpMM (CSR gather) ----------------
__global__ __launch_bounds__(384) void spmm_csr(
        const int* __restrict__ rp, const int* __restrict__ cp,
        const float* __restrict__ vp, const float* __restrict__ in,
        float* __restrict__ out, int nrows) {
    const int r = blockIdx.x;
    const int j = threadIdx.x;
    const int s = rp[r], e = rp[r + 1];
    float acc = 0.0f;
    for (int p = s; p < e; ++p) {
        int c = cp[p];
        float v = vp[p];
        acc = fmaf(v, in[(size_t)c * HD + j], acc);
    }
    out[(size_t)r * HD + j] = acc;
}

// ---------------- weight pack: fp32 [K,N] -> fragment-layout hi/lo bf16 ----------------
__global__ __launch_bounds__(256) void pack_w(
        const float* __restrict__ W, unsigned short* __restrict__ out,
        int KS, int NS, int N) {
    int t = blockIdx.x * 256 + threadIdx.x;
    int total = KS * NS * 64;
    if (t >= total) return;
    int l = t & 63;
    int ns = (t >> 6) % NS;
    int ks = t / (64 * NS);
    int col = ns * 16 + (l & 15);
    int k0 = ks * 32 + 8 * (l >> 4);
    size_t obase = (size_t)t * 8;
    size_t pstride = (size_t)KS * NS * 512;
    #pragma unroll
    for (int e = 0; e < 8; ++e) {
        float f = W[(size_t)(k0 + e) * N + col];
        unsigned u = __float_as_uint(f);
        unsigned short h = (unsigned short)(u >> 16);
        float r = f - __uint_as_float(u & 0xFFFF0000u);
        unsigned short lo = (unsigned short)(__float_as_uint(r) >> 16);
        out[obase + e] = (unsigned short)h;
        out[pstride + obase + e] = lo;
    }
}

__device__ __forceinline__ void split8(float4 a, float4 b, bf16x8& h, bf16x8& l) {
    float f[8] = {a.x, a.y, a.z, a.w, b.x, b.y, b.z, b.w};
    #pragma unroll
    for (int e = 0; e < 8; ++e) {
        unsigned u = __float_as_uint(f[e]);
        h[e] = (short)(unsigned short)(u >> 16);
        float r = f[e] - __uint_as_float(u & 0xFFFF0000u);
        l[e] = (short)(unsigned short)(__float_as_uint(r) >> 16);
    }
}

// ---------------- split-bf16 MFMA GEMM; 16-row M-tile/block, N split over 4 waves ----
// MODE 0: out = gelu(LN(A@W, gamma, beta))                       (word GCN 1,2)
// MODE 5: out = 0.35*aux1 + 0.65*gelu(LN(A@W, gamma, beta))      (word GCN 3 + residual)
// MODE 1: out = gelu(A@W + bias)                                 (gate1; A=[A1|A2])
// MODE 2: g = sigmoid(A@W + bias); out = g*aux1 + (1-g)*aux2     (gate2 + mix)
// MODE 3: out = LN(gelu(A@W + bias), gamma, beta)                (mlp1)
// MODE 4: v = gelu(A@W + bias); out = v @ aux1 + gamma           (mlp2 + classifier)
template<int MODE, int NS, int KS, int KSPLIT>
__global__ __launch_bounds__(256) void gemm_mfma(
        const float* __restrict__ A1, const float* __restrict__ A2,
        const unsigned short* __restrict__ Wp,
        const float* __restrict__ bias, const float* __restrict__ gamma,
        const float* __restrict__ beta,
        const float* __restrict__ aux1, const float* __restrict__ aux2,
        float* __restrict__ out, int M) {
    constexpr int N = NS * 16;
    constexpr int NSW = NS / 4;          // ns-subtiles per wave
    const int tid = threadIdx.x;
    const int wave = tid >> 6, l = tid & 63;
    const int row_base = blockIdx.x * 16;
    const int arow = row_base + (l & 15);
    const bool arow_ok = arow < M;
    const int koff = 8 * (l >> 4);
    const size_t pstride = (size_t)KS * NS * 512;

    __shared__ float ps[4][16], pq[4][16];
    __shared__ float mean_s[16], rstd_s[16];
    __shared__ float plg[4][16][2];

    f32x4 acc[NSW];
    #pragma unroll
    for (int ns = 0; ns < NSW; ++ns)
        acc[ns] = f32x4{0.f, 0.f, 0.f, 0.f};

    for (int ks = 0; ks < KS; ++ks) {
        const float* Ap;
        int ksl;
        if (ks < KSPLIT) { Ap = A1; ksl = ks; }
        else             { Ap = A2; ksl = ks - KSPLIT; }
        bf16x8 ah, al;
        if (arow_ok) {
            const float* src = Ap + (size_t)arow * HD + ksl * 32 + koff;
            float4 a0 = *reinterpret_cast<const float4*>(src);
            float4 a1 = *reinterpret_cast<const float4*>(src + 4);
            split8(a0, a1, ah, al);
        } else {
            #pragma unroll
            for (int e = 0; e < 8; ++e) { ah[e] = 0; al[e] = 0; }
        }
        const unsigned short* Bp = Wp + (size_t)ks * NS * 512
                                   + (size_t)wave * NSW * 512 + (size_t)l * 8;
        #pragma unroll
        for (int ns = 0; ns < NSW; ++ns) {
            bf16x8 bh = *reinterpret_cast<const bf16x8*>(Bp + ns * 512);
            bf16x8 bl = *reinterpret_cast<const bf16x8*>(Bp + pstride + ns * 512);
            acc[ns] = __builtin_amdgcn_mfma_f32_16x16x32_bf16(ah, bh, acc[ns], 0, 0, 0);
            acc[ns] = __builtin_amdgcn_mfma_f32_16x16x32_bf16(al, bh, acc[ns], 0, 0, 0);
            acc[ns] = __builtin_amdgcn_mfma_f32_16x16x32_bf16(ah, bl, acc[ns], 0, 0, 0);
        }
    }

    // D layout: row = row_base + (l>>4)*4 + r, col = (wave*NSW+ns)*16 + (l&15)
    const int col_lane = l & 15;
    const int g4 = (l >> 4) * 4;        // local row group base
    constexpr float invN = 1.0f / (float)N;

    if constexpr (MODE == 0 || MODE == 3 || MODE == 5) {
        if constexpr (MODE == 3) {
            #pragma unroll
            for (int ns = 0; ns < NSW; ++ns) {
                float bb = bias[(wave * NSW + ns) * 16 + col_lane];
                #pragma unroll
                for (int r = 0; r < 4; ++r)
                    acc[ns][r] = gelu_f(acc[ns][r] + bb);
            }
        }
        float s[4] = {0.f, 0.f, 0.f, 0.f}, q[4] = {0.f, 0.f, 0.f, 0.f};
        #pragma unroll
        for (int ns = 0; ns < NSW; ++ns)
            #pragma unroll
            for (int r = 0; r < 4; ++r) {
                float v = acc[ns][r];
                s[r] += v;
                q[r] += v * v;
            }
        #pragma unroll
        for (int r = 0; r < 4; ++r) {
            #pragma unroll
            for (int m = 1; m < 16; m <<= 1) {
                s[r] += __shfl_xor(s[r], m);
                q[r] += __shfl_xor(q[r], m);
            }
        }
        if (col_lane == 0) {
            #pragma unroll
            for (int r = 0; r < 4; ++r) {
                ps[wave][g4 + r] = s[r];
                pq[wave][g4 + r] = q[r];
            }
        }
        __syncthreads();
        if (tid < 16) {
            float ss = ps[0][tid] + ps[1][tid] + ps[2][tid] + ps[3][tid];
            float qq = pq[0][tid] + pq[1][tid] + pq[2][tid] + pq[3][tid];
            float m = ss * invN;
            mean_s[tid] = m;
            rstd_s[tid] = rsqrtf(qq * invN - m * m + 1e-5f);
        }
        __syncthreads();
        #pragma unroll
        for (int ns = 0; ns < NSW; ++ns) {
            int col = (wave * NSW + ns) * 16 + col_lane;
            float gg = gamma[col], bb = beta[col];
            #pragma unroll
            for (int r = 0; r < 4; ++r) {
                int row = row_base + g4 + r;
                if (row < M) {
                    float y = (acc[ns][r] - mean_s[g4 + r]) * rstd_s[g4 + r] * gg + bb;
                    if constexpr (MODE == 0)
                        out[(size_t)row * N + col] = gelu_f(y);
                    else if constexpr (MODE == 5)
                        out[(size_t)row * N + col] =
                            0.35f * aux1[(size_t)row * N + col] + 0.65f * gelu_f(y);
                    else
                        out[(size_t)row * N + col] = y;
                }
            }
        }
    } else if constexpr (MODE == 1) {
        #pragma unroll
        for (int ns = 0; ns < NSW; ++ns) {
            int col = (wave * NSW + ns) * 16 + col_lane;
            float bb = bias[col];
            #pragma unroll
            for (int r = 0; r < 4; ++r) {
                int row = row_base + g4 + r;
                if (row < M)
                    out[(size_t)row * N + col] = gelu_f(acc[ns][r] + bb);
            }
        }
    } else if constexpr (MODE == 2) {
        #pragma unroll
        for (int ns = 0; ns < NSW; ++ns) {
            int col = (wave * NSW + ns) * 16 + col_lane;
            float bb = bias[col];
            #pragma unroll
            for (int r = 0; r < 4; ++r) {
                int row = row_base + g4 + r;
                if (row < M) {
                    float g = sigmoid_f(acc[ns][r] + bb);
                    float h1 = aux1[(size_t)row * N + col];
                    float h0 = aux2[(size_t)row * N + col];
                    out[(size_t)row * N + col] = g * h1 + (1.0f - g) * h0;
                }
            }
        }
    } else if constexpr (MODE == 4) {
        float lg0[4] = {0.f, 0.f, 0.f, 0.f}, lg1[4] = {0.f, 0.f, 0.f, 0.f};
        #pragma unroll
        for (int ns = 0; ns < NSW; ++ns) {
            int col = (wave * NSW + ns) * 16 + col_lane;
            float bb = bias[col];
            float c0 = aux1[col * 2 + 0];
            float c1 = aux1[col * 2 + 1];
            #pragma unroll
            for (int r = 0; r < 4; ++r) {
                float v = gelu_f(acc[ns][r] + bb);
                lg0[r] = fmaf(v, c0, lg0[r]);
                lg1[r] = fmaf(v, c1, lg1[r]);
            }
        }
        #pragma unroll
        for (int r = 0; r < 4; ++r) {
            #pragma unroll
            for (int m = 1; m < 16; m <<= 1) {
                lg0[r] += __shfl_xor(lg0[r], m);
                lg1[r] += __shfl_xor(lg1[r], m);
            }
        }
        if (col_lane == 0) {
            #pragma unroll
            for (int r = 0; r < 4; ++r) {
                plg[wave][g4 + r][0] = lg0[r];
                plg[wave][g4 + r][1] = lg1[r];
            }
        }
        __syncthreads();
        if (tid < 32) {
            int rloc = tid >> 1, c = tid & 1;
            int row = row_base + rloc;
            if (row < M) {
                float t = plg[0][rloc][c] + plg[1][rloc][c]
                        + plg[2][rloc][c] + plg[3][rloc][c];
                out[(size_t)row * 2 + c] = t + gamma[c];
            }
        }
    }
}

static void build_csr(const int* rows, const int* cols, const float* vals,
                      int nnz, int n, int* rp, int* cp, float* vp,
                      int* cnt, int* bsum, int* boff, hipStream_t stream) {
    hipMemsetAsync(cnt, 0, (size_t)n * sizeof(int), stream);
    hist_rows<<<(nnz + 255) / 256, 256, 0, stream>>>(rows, cnt, nnz);
    int nb = (n + 255) / 256;
    scan_local<<<nb, 256, 0, stream>>>(cnt, rp, bsum, n);
    scan_bsums<<<1, 256, 0, stream>>>(bsum, boff, nb, rp + n);
    scan_add<<<nb, 256, 0, stream>>>(rp, boff, n);
    hipMemsetAsync(cnt, 0, (size_t)n * sizeof(int), stream);
    csr_scatter<<<(nnz + 255) / 256, 256, 0, stream>>>(rows, cols, vals, rp, cnt, cp, vp, nnz);
}

extern "C" void kernel_launch(void* const* d_in, const int* in_sizes, int n_in,
                              void* d_out, int out_size, void* d_ws, size_t ws_size,
                              hipStream_t stream) {
    const int*   A_rows = (const int*)  d_in[0];
    const int*   A_cols = (const int*)  d_in[1];
    const float* A_vals = (const float*)d_in[2];
    const int*   X_rows = (const int*)  d_in[3];
    const int*   X_cols = (const int*)  d_in[4];
    const float* X_vals = (const float*)d_in[5];
    const float* emb    = (const float*)d_in[7];
    const float* W1     = (const float*)d_in[8];
    const float* W2     = (const float*)d_in[9];
    const float* W3     = (const float*)d_in[10];
    const float* g1     = (const float*)d_in[11];
    const float* b1     = (const float*)d_in[12];
    const float* g2     = (const float*)d_in[13];
    const float* b2     = (const float*)d_in[14];
    const float* g3     = (const float*)d_in[15];
    const float* b3     = (const float*)d_in[16];
    const float* mW1    = (const float*)d_in[17];
    const float* mb1    = (const float*)d_in[18];
    const float* mg     = (const float*)d_in[19];
    const float* mbn    = (const float*)d_in[20];
    const float* mW2    = (const float*)d_in[21];
    const float* mb2    = (const float*)d_in[22];
    const float* cW     = (const float*)d_in[23];
    const float* cb     = (const float*)d_in[24];
    const float* gW1    = (const float*)d_in[25];
    const float* gb1    = (const float*)d_in[26];
    const float* gW2    = (const float*)d_in[27];
    const float* gb2    = (const float*)d_in[28];

    const int E_   = in_sizes[0];
    const int NNZ_ = in_sizes[3];
    const int N_   = in_sizes[7] / HD;
    const int D_   = out_size / 2;

    // ---- workspace layout ----
    float* buf1 = (float*)d_ws;                       // [N, H]
    float* buf2 = buf1 + (size_t)N_ * HD;             // [N, H]
    int*   A_rp = (int*)(buf2 + (size_t)N_ * HD);
    int*   A_cp = A_rp + (N_ + 1);
    float* A_vp = (float*)(A_cp + E_);
    int*   X_rp = (int*)(A_vp + E_);
    int*   X_cp = X_rp + (D_ + 1);
    float* X_vp = (float*)(X_cp + NNZ_);
    int*   cnt  = (int*)(X_vp + NNZ_);
    int*   bsum = cnt + N_;
    int*   boff = bsum + 256;
    size_t pk_off = ((size_t)(boff + 256 - (int*)d_ws) + 7) & ~(size_t)7;
    unsigned short* packs = (unsigned short*)((float*)d_ws + pk_off);
    const size_t SZ_SQ = (size_t)2 * HD * HD;
    unsigned short* p_W1  = packs;
    unsigned short* p_W2  = p_W1  + SZ_SQ;
    unsigned short* p_W3  = p_W2  + SZ_SQ;
    unsigned short* p_gW2 = p_W3  + SZ_SQ;
    unsigned short* p_mW1 = p_gW2 + SZ_SQ;
    unsigned short* p_gW1 = p_mW1 + SZ_SQ;
    unsigned short* p_mW2 = p_gW1 + (size_t)2 * 2 * HD * HD;

    float* dbuf1 = buf2;                              // [D, H] docH
    float* dbuf2 = buf2 + (size_t)D_ * HD;            // [D, H] docH0
    float* t1    = buf1;                              // [D, H] (word_H dead by then)
    float* dmix  = buf1 + (size_t)D_ * HD;            // [D, H]
    float* un    = buf1;                              // [D, H] (t1 dead by then)
    float* logits = (float*)d_out;

    const int word_grid = (N_ + 15) / 16;             // 2500
    const int doc_grid  = (D_ + 15) / 16;             // 1250

    // ---- pack weights ----
    pack_w<<<(12 * 24 * 64 + 255) / 256, 256, 0, stream>>>(W1,  p_W1,  12, 24, HD);
    pack_w<<<(12 * 24 * 64 + 255) / 256, 256, 0, stream>>>(W2,  p_W2,  12, 24, HD);
    pack_w<<<(12 * 24 * 64 + 255) / 256, 256, 0, stream>>>(W3,  p_W3,  12, 24, HD);
    pack_w<<<(12 * 24 * 64 + 255) / 256, 256, 0, stream>>>(gW2, p_gW2, 12, 24, HD);
    pack_w<<<(12 * 24 * 64 + 255) / 256, 256, 0, stream>>>(mW1, p_mW1, 12, 24, HD);
    pack_w<<<(24 * 24 * 64 + 255) / 256, 256, 0, stream>>>(gW1, p_gW1, 24, 24, HD);
    pack_w<<<(12 * 12 * 64 + 255) / 256, 256, 0, stream>>>(mW2, p_mW2, 12, 12, HHD);

    // ---- build CSR ----
    build_csr(A_rows, A_cols, A_vals, E_, N_, A_rp, A_cp, A_vp, cnt, bsum, boff, stream);
    build_csr(X_rows, X_cols, X_vals, NNZ_, D_, X_rp, X_cp, X_vp, cnt, bsum, boff, stream);

    // ---- GCN blocks ----
    spmm_csr<<<N_, 384, 0, stream>>>(A_rp, A_cp, A_vp, emb, buf1, N_);
    gemm_mfma<0, 24, 12, 12><<<word_grid, 256, 0, stream>>>(
        buf1, nullptr, p_W1, nullptr, g1, b1, nullptr, nullptr, buf2, N_);
    spmm_csr<<<N_, 384, 0, stream>>>(A_rp, A_cp, A_vp, buf2, buf1, N_);
    gemm_mfma<0, 24, 12, 12><<<word_grid, 256, 0, stream>>>(
        buf1, nullptr, p_W2, nullptr, g2, b2, nullptr, nullptr, buf2, N_);
    spmm_csr<<<N_, 384, 0, stream>>>(A_rp, A_cp, A_vp, buf2, buf1, N_);
    // block 3 with fused residual: word_H = 0.35*emb + 0.65*gelu(LN(...)), in-place
    gemm_mfma<5, 24, 12, 12><<<word_grid, 256, 0, stream>>>(
        buf1, nullptr, p_W3, nullptr, g3, b3, emb, nullptr, buf1, N_);

    // ---- doc aggregation (word_H in buf1) ----
    spmm_csr<<<D_, 384, 0, stream>>>(X_rp, X_cp, X_vp, buf1, dbuf1, D_);
    spmm_csr<<<D_, 384, 0, stream>>>(X_rp, X_cp, X_vp, emb, dbuf2, D_);

    // ---- doc head ----
    gemm_mfma<1, 24, 24, 12><<<doc_grid, 256, 0, stream>>>(
        dbuf1, dbuf2, p_gW1, gb1, nullptr, nullptr, nullptr, nullptr, t1, D_);
    gemm_mfma<2, 24, 12, 12><<<doc_grid, 256, 0, stream>>>(
        t1, nullptr, p_gW2, gb2, nullptr, nullptr, dbuf1, dbuf2, dmix, D_);
    gemm_mfma<3, 24, 12, 12><<<doc_grid, 256, 0, stream>>>(
        dmix, nullptr, p_mW1, mb1, mg, mbn, nullptr, nullptr, un, D_);
    gemm_mfma<4, 12, 12, 12><<<doc_grid, 256, 0, stream>>>(
        un, nullptr, p_mW2, mb2, cb, nullptr, cW, nullptr, logits, D_);
}

// Round 6
// 1721.319 us; speedup vs baseline: 13.3045x; 1.2212x over previous
//
#include <hip/hip_runtime.h>
#include <hip/hip_fp16.h>

#define HD 384
#define HHD 192

using bf16x8 = __attribute__((ext_vector_type(8))) short;
using f32x4  = __attribute__((ext_vector_type(4))) float;

__device__ __forceinline__ float gelu_f(float x) {
    return 0.5f * x * (1.0f + erff(x * 0.70710678118654752f));
}

__device__ __forceinline__ float sigmoid_f(float x) {
    return 1.0f / (1.0f + expf(-x));
}

// ---------------- CSR build ----------------
__global__ __launch_bounds__(256) void hist_rows(
        const int* __restrict__ rows, int* __restrict__ cnt, int nnz) {
    int e = blockIdx.x * blockDim.x + threadIdx.x;
    if (e < nnz) atomicAdd(&cnt[rows[e]], 1);
}

__global__ __launch_bounds__(256) void scan_local(
        const int* __restrict__ cnt, int* __restrict__ rp,
        int* __restrict__ bsum, int n) {
    __shared__ int wsum[4];
    int i = blockIdx.x * 256 + threadIdx.x;
    int lane = threadIdx.x & 63, wv = threadIdx.x >> 6;
    int v = (i < n) ? cnt[i] : 0;
    int s = v;
    #pragma unroll
    for (int o = 1; o < 64; o <<= 1) {
        int t = __shfl_up(s, o);
        if (lane >= o) s += t;
    }
    if (lane == 63) wsum[wv] = s;
    __syncthreads();
    int woff = 0;
    for (int w = 0; w < wv; ++w) woff += wsum[w];
    if (i < n) rp[i] = woff + s - v;
    if (threadIdx.x == 255) bsum[blockIdx.x] = woff + s;
}

__global__ __launch_bounds__(256) void scan_bsums(
        const int* __restrict__ bsum, int* __restrict__ boff,
        int nb, int* __restrict__ total_out) {
    __shared__ int tmp[256];
    int tid = threadIdx.x;
    int v = (tid < nb) ? bsum[tid] : 0;
    tmp[tid] = v;
    __syncthreads();
    for (int o = 1; o < 256; o <<= 1) {
        int t = (tid >= o) ? tmp[tid - o] : 0;
        __syncthreads();
        tmp[tid] += t;
        __syncthreads();
    }
    if (tid < nb) boff[tid] = tmp[tid] - v;
    if (tid == nb - 1) *total_out = tmp[tid];
}

__global__ __launch_bounds__(256) void scan_add(
        int* __restrict__ rp, const int* __restrict__ boff, int n) {
    int i = blockIdx.x * 256 + threadIdx.x;
    if (i < n) rp[i] += boff[i >> 8];
}

__global__ __launch_bounds__(256) void csr_scatter(
        const int* __restrict__ rows, const int* __restrict__ cols,
        const float* __restrict__ vals, const int* __restrict__ rp,
        int* __restrict__ fill, int* __restrict__ cp,
        float* __restrict__ vp, int nnz) {
    int e = blockIdx.x * blockDim.x + threadIdx.x;
    if (e >= nnz) return;
    int r = rows[e];
    int pos = rp[r] + atomicAdd(&fill[r], 1);
    cp[pos] = cols[e];
    vp[pos] = vals[e];
}

// ---------------- fp32 -> fp16 convert ----------------
__global__ __launch_bounds__(256) void cvt_fp16(
        const float* __restrict__ in, __half2* __restrict__ out, int n2) {
    int i = blockIdx.x * blockDim.x + threadIdx.x;
    if (i >= n2) return;
    float2 v = reinterpret_cast<const float2*>(in)[i];
    out[i] = __floats2half2_rn(v.x, v.y);
}

// ---------------- SpMM (CSR gather, fp16 table, fp32 out) ----------------
// 2 rows / block; 192 threads per row; half2 per thread.
__global__ __launch_bounds__(384) void spmm_h2(
        const int* __restrict__ rp, const int* __restrict__ cp,
        const float* __restrict__ vp, const __half2* __restrict__ in,
        float* __restrict__ out, int nrows) {
    const int t  = threadIdx.x % HHD;
    const int r  = blockIdx.x * 2 + threadIdx.x / HHD;
    if (r >= nrows) return;
    const int s = rp[r], e = rp[r + 1];
    float ax = 0.f, ay = 0.f;
    for (int p = s; p < e; ++p) {
        int c = cp[p];
        float v = vp[p];
        float2 x = __half22float2(in[(size_t)c * HHD + t]);
        ax = fmaf(v, x.x, ax);
        ay = fmaf(v, x.y, ay);
    }
    reinterpret_cast<float2*>(out)[(size_t)r * HHD + t] = make_float2(ax, ay);
}

// ---------------- fused doc SpMM: docH0 = X@emb, docH = 0.35*docH0 + 0.65*X@h3 ----
__global__ __launch_bounds__(384) void spmm_doc2(
        const int* __restrict__ rp, const int* __restrict__ cp,
        const float* __restrict__ vp,
        const __half2* __restrict__ inH, const __half2* __restrict__ inE,
        float* __restrict__ docH, float* __restrict__ docH0, int nrows) {
    const int t  = threadIdx.x % HHD;
    const int r  = blockIdx.x * 2 + threadIdx.x / HHD;
    if (r >= nrows) return;
    const int s = rp[r], e = rp[r + 1];
    float hx = 0.f, hy = 0.f, ex = 0.f, ey = 0.f;
    for (int p = s; p < e; ++p) {
        int c = cp[p];
        float v = vp[p];
        float2 xh = __half22float2(inH[(size_t)c * HHD + t]);
        float2 xe = __half22float2(inE[(size_t)c * HHD + t]);
        hx = fmaf(v, xh.x, hx);
        hy = fmaf(v, xh.y, hy);
        ex = fmaf(v, xe.x, ex);
        ey = fmaf(v, xe.y, ey);
    }
    reinterpret_cast<float2*>(docH0)[(size_t)r * HHD + t] = make_float2(ex, ey);
    reinterpret_cast<float2*>(docH)[(size_t)r * HHD + t] =
        make_float2(0.35f * ex + 0.65f * hx, 0.35f * ey + 0.65f * hy);
}

// ---------------- weight pack: fp32 [K,N] -> fragment-layout hi/lo bf16 ----------------
__global__ __launch_bounds__(256) void pack_w(
        const float* __restrict__ W, unsigned short* __restrict__ out,
        int KS, int NS, int N) {
    int t = blockIdx.x * 256 + threadIdx.x;
    int total = KS * NS * 64;
    if (t >= total) return;
    int l = t & 63;
    int ns = (t >> 6) % NS;
    int ks = t / (64 * NS);
    int col = ns * 16 + (l & 15);
    int k0 = ks * 32 + 8 * (l >> 4);
    size_t obase = (size_t)t * 8;
    size_t pstride = (size_t)KS * NS * 512;
    #pragma unroll
    for (int e = 0; e < 8; ++e) {
        float f = W[(size_t)(k0 + e) * N + col];
        unsigned u = __float_as_uint(f);
        unsigned short h = (unsigned short)(u >> 16);
        float r = f - __uint_as_float(u & 0xFFFF0000u);
        unsigned short lo = (unsigned short)(__float_as_uint(r) >> 16);
        out[obase + e] = (unsigned short)h;
        out[pstride + obase + e] = lo;
    }
}

__device__ __forceinline__ void split8(float4 a, float4 b, bf16x8& h, bf16x8& l) {
    float f[8] = {a.x, a.y, a.z, a.w, b.x, b.y, b.z, b.w};
    #pragma unroll
    for (int e = 0; e < 8; ++e) {
        unsigned u = __float_as_uint(f[e]);
        h[e] = (short)(unsigned short)(u >> 16);
        float r = f[e] - __uint_as_float(u & 0xFFFF0000u);
        l[e] = (short)(unsigned short)(__float_as_uint(r) >> 16);
    }
}

// ---------------- split-bf16 MFMA GEMM; 16-row M-tile/block, N split over 4 waves ----
// MODE 0: y = gelu(LN(A@W, gamma, beta))            (word GCN; OUT16 -> fp16 out)
// MODE 1: out = gelu(A@W + bias)                    (gate1; A=[A1|A2])
// MODE 2: g = sigmoid(A@W + bias); out = g*aux1 + (1-g)*aux2
// MODE 3: out = LN(gelu(A@W + bias), gamma, beta)   (mlp1)
// MODE 4: v = gelu(A@W + bias); out = v @ aux1 + gamma  (mlp2 + classifier)
template<int MODE, int NS, int KS, int KSPLIT, bool OUT16>
__global__ __launch_bounds__(256) void gemm_mfma(
        const float* __restrict__ A1, const float* __restrict__ A2,
        const unsigned short* __restrict__ Wp,
        const float* __restrict__ bias, const float* __restrict__ gamma,
        const float* __restrict__ beta,
        const float* __restrict__ aux1, const float* __restrict__ aux2,
        float* __restrict__ out, int M) {
    constexpr int N = NS * 16;
    constexpr int NSW = NS / 4;
    const int tid = threadIdx.x;
    const int wave = tid >> 6, l = tid & 63;
    const int row_base = blockIdx.x * 16;
    const int arow = row_base + (l & 15);
    const bool arow_ok = arow < M;
    const int koff = 8 * (l >> 4);
    const size_t pstride = (size_t)KS * NS * 512;

    __shared__ float ps[4][16], pq[4][16];
    __shared__ float mean_s[16], rstd_s[16];
    __shared__ float plg[4][16][2];

    f32x4 acc[NSW];
    #pragma unroll
    for (int ns = 0; ns < NSW; ++ns)
        acc[ns] = f32x4{0.f, 0.f, 0.f, 0.f};

    for (int ks = 0; ks < KS; ++ks) {
        const float* Ap;
        int ksl;
        if (ks < KSPLIT) { Ap = A1; ksl = ks; }
        else             { Ap = A2; ksl = ks - KSPLIT; }
        bf16x8 ah, al;
        if (arow_ok) {
            const float* src = Ap + (size_t)arow * HD + ksl * 32 + koff;
            float4 a0 = *reinterpret_cast<const float4*>(src);
            float4 a1 = *reinterpret_cast<const float4*>(src + 4);
            split8(a0, a1, ah, al);
        } else {
            #pragma unroll
            for (int e = 0; e < 8; ++e) { ah[e] = 0; al[e] = 0; }
        }
        const unsigned short* Bp = Wp + (size_t)ks * NS * 512
                                   + (size_t)wave * NSW * 512 + (size_t)l * 8;
        #pragma unroll
        for (int ns = 0; ns < NSW; ++ns) {
            bf16x8 bh = *reinterpret_cast<const bf16x8*>(Bp + ns * 512);
            bf16x8 bl = *reinterpret_cast<const bf16x8*>(Bp + pstride + ns * 512);
            acc[ns] = __builtin_amdgcn_mfma_f32_16x16x32_bf16(ah, bh, acc[ns], 0, 0, 0);
            acc[ns] = __builtin_amdgcn_mfma_f32_16x16x32_bf16(al, bh, acc[ns], 0, 0, 0);
            acc[ns] = __builtin_amdgcn_mfma_f32_16x16x32_bf16(ah, bl, acc[ns], 0, 0, 0);
        }
    }

    const int col_lane = l & 15;
    const int g4 = (l >> 4) * 4;
    constexpr float invN = 1.0f / (float)N;

    if constexpr (MODE == 0 || MODE == 3) {
        if constexpr (MODE == 3) {
            #pragma unroll
            for (int ns = 0; ns < NSW; ++ns) {
                float bb = bias[(wave * NSW + ns) * 16 + col_lane];
                #pragma unroll
                for (int r = 0; r < 4; ++r)
                    acc[ns][r] = gelu_f(acc[ns][r] + bb);
            }
        }
        float s[4] = {0.f, 0.f, 0.f, 0.f}, q[4] = {0.f, 0.f, 0.f, 0.f};
        #pragma unroll
        for (int ns = 0; ns < NSW; ++ns)
            #pragma unroll
            for (int r = 0; r < 4; ++r) {
                float v = acc[ns][r];
                s[r] += v;
                q[r] += v * v;
            }
        #pragma unroll
        for (int r = 0; r < 4; ++r) {
            #pragma unroll
            for (int m = 1; m < 16; m <<= 1) {
                s[r] += __shfl_xor(s[r], m);
                q[r] += __shfl_xor(q[r], m);
            }
        }
        if (col_lane == 0) {
            #pragma unroll
            for (int r = 0; r < 4; ++r) {
                ps[wave][g4 + r] = s[r];
                pq[wave][g4 + r] = q[r];
            }
        }
        __syncthreads();
        if (tid < 16) {
            float ss = ps[0][tid] + ps[1][tid] + ps[2][tid] + ps[3][tid];
            float qq = pq[0][tid] + pq[1][tid] + pq[2][tid] + pq[3][tid];
            float m = ss * invN;
            mean_s[tid] = m;
            rstd_s[tid] = rsqrtf(qq * invN - m * m + 1e-5f);
        }
        __syncthreads();
        #pragma unroll
        for (int ns = 0; ns < NSW; ++ns) {
            int col = (wave * NSW + ns) * 16 + col_lane;
            float gg = gamma[col], bb = beta[col];
            #pragma unroll
            for (int r = 0; r < 4; ++r) {
                int row = row_base + g4 + r;
                if (row < M) {
                    float y = (acc[ns][r] - mean_s[g4 + r]) * rstd_s[g4 + r] * gg + bb;
                    if constexpr (MODE == 0) {
                        y = gelu_f(y);
                        if constexpr (OUT16)
                            reinterpret_cast<__half*>(out)[(size_t)row * N + col] =
                                __float2half(y);
                        else
                            out[(size_t)row * N + col] = y;
                    } else {
                        out[(size_t)row * N + col] = y;
                    }
                }
            }
        }
    } else if constexpr (MODE == 1) {
        #pragma unroll
        for (int ns = 0; ns < NSW; ++ns) {
            int col = (wave * NSW + ns) * 16 + col_lane;
            float bb = bias[col];
            #pragma unroll
            for (int r = 0; r < 4; ++r) {
                int row = row_base + g4 + r;
                if (row < M)
                    out[(size_t)row * N + col] = gelu_f(acc[ns][r] + bb);
            }
        }
    } else if constexpr (MODE == 2) {
        #pragma unroll
        for (int ns = 0; ns < NSW; ++ns) {
            int col = (wave * NSW + ns) * 16 + col_lane;
            float bb = bias[col];
            #pragma unroll
            for (int r = 0; r < 4; ++r) {
                int row = row_base + g4 + r;
                if (row < M) {
                    float g = sigmoid_f(acc[ns][r] + bb);
                    float h1 = aux1[(size_t)row * N + col];
                    float h0 = aux2[(size_t)row * N + col];
                    out[(size_t)row * N + col] = g * h1 + (1.0f - g) * h0;
                }
            }
        }
    } else if constexpr (MODE == 4) {
        float lg0[4] = {0.f, 0.f, 0.f, 0.f}, lg1[4] = {0.f, 0.f, 0.f, 0.f};
        #pragma unroll
        for (int ns = 0; ns < NSW; ++ns) {
            int col = (wave * NSW + ns) * 16 + col_lane;
            float bb = bias[col];
            float c0 = aux1[col * 2 + 0];
            float c1 = aux1[col * 2 + 1];
            #pragma unroll
            for (int r = 0; r < 4; ++r) {
                float v = gelu_f(acc[ns][r] + bb);
                lg0[r] = fmaf(v, c0, lg0[r]);
                lg1[r] = fmaf(v, c1, lg1[r]);
            }
        }
        #pragma unroll
        for (int r = 0; r < 4; ++r) {
            #pragma unroll
            for (int m = 1; m < 16; m <<= 1) {
                lg0[r] += __shfl_xor(lg0[r], m);
                lg1[r] += __shfl_xor(lg1[r], m);
            }
        }
        if (col_lane == 0) {
            #pragma unroll
            for (int r = 0; r < 4; ++r) {
                plg[wave][g4 + r][0] = lg0[r];
                plg[wave][g4 + r][1] = lg1[r];
            }
        }
        __syncthreads();
        if (tid < 32) {
            int rloc = tid >> 1, c = tid & 1;
            int row = row_base + rloc;
            if (row < M) {
                float t = plg[0][rloc][c] + plg[1][rloc][c]
                        + plg[2][rloc][c] + plg[3][rloc][c];
                out[(size_t)row * 2 + c] = t + gamma[c];
            }
        }
    }
}

static void build_csr(const int* rows, const int* cols, const float* vals,
                      int nnz, int n, int* rp, int* cp, float* vp,
                      int* cnt, int* bsum, int* boff, hipStream_t stream) {
    hipMemsetAsync(cnt, 0, (size_t)n * sizeof(int), stream);
    hist_rows<<<(nnz + 255) / 256, 256, 0, stream>>>(rows, cnt, nnz);
    int nb = (n + 255) / 256;
    scan_local<<<nb, 256, 0, stream>>>(cnt, rp, bsum, n);
    scan_bsums<<<1, 256, 0, stream>>>(bsum, boff, nb, rp + n);
    scan_add<<<nb, 256, 0, stream>>>(rp, boff, n);
    hipMemsetAsync(cnt, 0, (size_t)n * sizeof(int), stream);
    csr_scatter<<<(nnz + 255) / 256, 256, 0, stream>>>(rows, cols, vals, rp, cnt, cp, vp, nnz);
}

extern "C" void kernel_launch(void* const* d_in, const int* in_sizes, int n_in,
                              void* d_out, int out_size, void* d_ws, size_t ws_size,
                              hipStream_t stream) {
    const int*   A_rows = (const int*)  d_in[0];
    const int*   A_cols = (const int*)  d_in[1];
    const float* A_vals = (const float*)d_in[2];
    const int*   X_rows = (const int*)  d_in[3];
    const int*   X_cols = (const int*)  d_in[4];
    const float* X_vals = (const float*)d_in[5];
    const float* emb    = (const float*)d_in[7];
    const float* W1     = (const float*)d_in[8];
    const float* W2     = (const float*)d_in[9];
    const float* W3     = (const float*)d_in[10];
    const float* g1     = (const float*)d_in[11];
    const float* b1     = (const float*)d_in[12];
    const float* g2     = (const float*)d_in[13];
    const float* b2     = (const float*)d_in[14];
    const float* g3     = (const float*)d_in[15];
    const float* b3     = (const float*)d_in[16];
    const float* mW1    = (const float*)d_in[17];
    const float* mb1    = (const float*)d_in[18];
    const float* mg     = (const float*)d_in[19];
    const float* mbn    = (const float*)d_in[20];
    const float* mW2    = (const float*)d_in[21];
    const float* mb2    = (const float*)d_in[22];
    const float* cW     = (const float*)d_in[23];
    const float* cb     = (const float*)d_in[24];
    const float* gW1    = (const float*)d_in[25];
    const float* gb1    = (const float*)d_in[26];
    const float* gW2    = (const float*)d_in[27];
    const float* gb2    = (const float*)d_in[28];

    const int E_   = in_sizes[0];
    const int NNZ_ = in_sizes[3];
    const int N_   = in_sizes[7] / HD;
    const int D_   = out_size / 2;

    // ---- workspace layout ----
    float*   buf1  = (float*)d_ws;                         // [N,H] fp32
    __half2* t16   = (__half2*)(buf1 + (size_t)N_ * HD);   // [N,H] fp16 (N*H/2 half2)
    __half2* emb16 = t16 + (size_t)N_ * HHD;               // [N,H] fp16
    int*   A_rp = (int*)(emb16 + (size_t)N_ * HHD);
    int*   A_cp = A_rp + (N_ + 1);
    float* A_vp = (float*)(A_cp + E_);
    int*   X_rp = (int*)(A_vp + E_);
    int*   X_cp = X_rp + (D_ + 1);
    float* X_vp = (float*)(X_cp + NNZ_);
    int*   cnt  = (int*)(X_vp + NNZ_);
    int*   bsum = cnt + N_;
    int*   boff = bsum + 256;
    size_t pk_off = ((size_t)(boff + 256 - (int*)d_ws) + 7) & ~(size_t)7;
    unsigned short* packs = (unsigned short*)((float*)d_ws + pk_off);
    const size_t SZ_SQ = (size_t)2 * HD * HD;
    unsigned short* p_W1  = packs;
    unsigned short* p_W2  = p_W1  + SZ_SQ;
    unsigned short* p_W3  = p_W2  + SZ_SQ;
    unsigned short* p_gW2 = p_W3  + SZ_SQ;
    unsigned short* p_mW1 = p_gW2 + SZ_SQ;
    unsigned short* p_gW1 = p_mW1 + SZ_SQ;
    unsigned short* p_mW2 = p_gW1 + (size_t)2 * 2 * HD * HD;

    // doc-phase aliases
    float* docH  = buf1;                         // [D,H]
    float* docH0 = buf1 + (size_t)D_ * HD;       // [D,H]  (D*H*2 == N*H)
    float* t1    = (float*)t16;                  // [D,H] fp32 (N*H/2 floats == D*H)
    float* dmix  = (float*)emb16;                // [D,H] fp32
    float* un    = buf1;                         // [D,H] (docH dead by then)
    float* logits = (float*)d_out;

    const int word_grid = (N_ + 15) / 16;
    const int doc_grid  = (D_ + 15) / 16;

    // ---- pack weights ----
    pack_w<<<(12 * 24 * 64 + 255) / 256, 256, 0, stream>>>(W1,  p_W1,  12, 24, HD);
    pack_w<<<(12 * 24 * 64 + 255) / 256, 256, 0, stream>>>(W2,  p_W2,  12, 24, HD);
    pack_w<<<(12 * 24 * 64 + 255) / 256, 256, 0, stream>>>(W3,  p_W3,  12, 24, HD);
    pack_w<<<(12 * 24 * 64 + 255) / 256, 256, 0, stream>>>(gW2, p_gW2, 12, 24, HD);
    pack_w<<<(12 * 24 * 64 + 255) / 256, 256, 0, stream>>>(mW1, p_mW1, 12, 24, HD);
    pack_w<<<(24 * 24 * 64 + 255) / 256, 256, 0, stream>>>(gW1, p_gW1, 24, 24, HD);
    pack_w<<<(12 * 12 * 64 + 255) / 256, 256, 0, stream>>>(mW2, p_mW2, 12, 12, HHD);

    // ---- emb -> fp16 ----
    cvt_fp16<<<((N_ * HHD) + 255) / 256, 256, 0, stream>>>(emb, emb16, N_ * HHD);

    // ---- build CSR ----
    build_csr(A_rows, A_cols, A_vals, E_, N_, A_rp, A_cp, A_vp, cnt, bsum, boff, stream);
    build_csr(X_rows, X_cols, X_vals, NNZ_, D_, X_rp, X_cp, X_vp, cnt, bsum, boff, stream);

    // ---- GCN blocks (SpMM gathers fp16, GEMM writes fp16) ----
    spmm_h2<<<(N_ + 1) / 2, 384, 0, stream>>>(A_rp, A_cp, A_vp, emb16, buf1, N_);
    gemm_mfma<0, 24, 12, 12, true><<<word_grid, 256, 0, stream>>>(
        buf1, nullptr, p_W1, nullptr, g1, b1, nullptr, nullptr, (float*)t16, N_);
    spmm_h2<<<(N_ + 1) / 2, 384, 0, stream>>>(A_rp, A_cp, A_vp, t16, buf1, N_);
    gemm_mfma<0, 24, 12, 12, true><<<word_grid, 256, 0, stream>>>(
        buf1, nullptr, p_W2, nullptr, g2, b2, nullptr, nullptr, (float*)t16, N_);
    spmm_h2<<<(N_ + 1) / 2, 384, 0, stream>>>(A_rp, A_cp, A_vp, t16, buf1, N_);
    gemm_mfma<0, 24, 12, 12, true><<<word_grid, 256, 0, stream>>>(
        buf1, nullptr, p_W3, nullptr, g3, b3, nullptr, nullptr, (float*)t16, N_);

    // ---- fused doc aggregation: docH0 = X@emb; docH = 0.35*docH0 + 0.65*X@h3 ----
    spmm_doc2<<<(D_ + 1) / 2, 384, 0, stream>>>(X_rp, X_cp, X_vp, t16, emb16,
                                                docH, docH0, D_);

    // ---- doc head ----
    gemm_mfma<1, 24, 24, 12, false><<<doc_grid, 256, 0, stream>>>(
        docH, docH0, p_gW1, gb1, nullptr, nullptr, nullptr, nullptr, t1, D_);
    gemm_mfma<2, 24, 12, 12, false><<<doc_grid, 256, 0, stream>>>(
        t1, nullptr, p_gW2, gb2, nullptr, nullptr, docH, docH0, dmix, D_);
    gemm_mfma<3, 24, 12, 12, false><<<doc_grid, 256, 0, stream>>>(
        dmix, nullptr, p_mW1, mb1, mg, mbn, nullptr, nullptr, un, D_);
    gemm_mfma<4, 12, 12, 12, false><<<doc_grid, 256, 0, stream>>>(
        un, nullptr, p_mW2, mb2, cb, nullptr, cW, nullptr, logits, D_);
}